// Round 1
// baseline (611.141 us; speedup 1.0000x reference)
//
#include <hip/hip_runtime.h>

typedef unsigned short u16;
typedef __attribute__((ext_vector_type(4))) unsigned short u16x4;
typedef __attribute__((ext_vector_type(8))) unsigned short u16x8;
typedef __attribute__((ext_vector_type(8))) short short8;
typedef __attribute__((ext_vector_type(4))) float f32x4;

#define DEVI __device__ __forceinline__

DEVI u16 f2b(float f) {
  union { float f; unsigned u; } x; x.f = f;
  unsigned r = (x.u + 0x7fffu + ((x.u >> 16) & 1u)) >> 16;
  return (u16)r;
}
DEVI float b2f(u16 h) {
  union { unsigned u; float f; } x; x.u = ((unsigned)h) << 16;
  return x.f;
}
DEVI f32x4 mfma_bf16(short8 a, short8 b, f32x4 c) {
  return __builtin_amdgcn_mfma_f32_16x16x32_bf16(a, b, c, 0, 0, 0);
}
DEVI void gl2lds16(const u16* g, u16* l) {
  __builtin_amdgcn_global_load_lds((__attribute__((address_space(1))) void*)g,
                                   (__attribute__((address_space(3))) void*)l,
                                   16, 0, 0);
}

// ---------------- fp32 -> bf16 convert (hidden_states) ----------------
__global__ void k_cvt(const float* __restrict__ src, u16* __restrict__ dst, int n4) {
  int i = blockIdx.x * 256 + threadIdx.x;
  if (i < n4) {
    float4 v = ((const float4*)src)[i];
    u16x4 r; r.x = f2b(v.x); r.y = f2b(v.y); r.z = f2b(v.z); r.w = f2b(v.w);
    ((u16x4*)dst)[i] = r;
  }
}

// ---------------- tiled transpose fp32[R][C] -> bf16[C][R] ----------------
__global__ void k_transpose(const float* __restrict__ src, u16* __restrict__ dst, int R, int C) {
  __shared__ float tile[32][33];
  int bx = blockIdx.x << 5, by = blockIdx.y << 5;
  int x = threadIdx.x, y = threadIdx.y;
#pragma unroll
  for (int j = 0; j < 32; j += 8)
    tile[y + j][x] = src[(size_t)(by + y + j) * C + bx + x];
  __syncthreads();
#pragma unroll
  for (int j = 0; j < 32; j += 8)
    dst[(size_t)(bx + y + j) * R + by + x] = f2b(tile[x][y + j]);
}

// ---------------- bf16 MFMA GEMM: C[M][N] = A[M][K] @ BT[N][K]^T ----------------
__global__ __launch_bounds__(256, 2)
void k_gemm_bt(const u16* __restrict__ A, const u16* __restrict__ BT,
               float* __restrict__ Cf, u16* __restrict__ Cb,
               int M, int N, int K, int outbf) {
  __shared__ __align__(16) u16 As[4096];
  __shared__ __align__(16) u16 Bs[4096];
  const int tid = threadIdx.x, wave = tid >> 6, lane = tid & 63;
  const long bm = (long)blockIdx.y << 7, bn = (long)blockIdx.x << 7;
  const int r0 = (wave << 4) + (lane >> 2), kof = (lane & 3) << 3;
  const u16* gA = A + (bm + r0) * (long)K + kof;
  const u16* gB = BT + (bn + r0) * (long)K + kof;
  u16* lA = As + (wave << 9);
  u16* lB = Bs + (wave << 9);
  const long stepR = (long)64 * K;
  const int wr = (wave >> 1) << 6, wc = (wave & 1) << 6;
  const int fr = lane & 15, fq = (lane >> 4) << 3;
  f32x4 acc[4][4];
#pragma unroll
  for (int i = 0; i < 4; ++i)
#pragma unroll
    for (int j = 0; j < 4; ++j) acc[i][j] = (f32x4){0.f, 0.f, 0.f, 0.f};
  for (int k0 = 0; k0 < K; k0 += 32) {
    gl2lds16(gA + k0, lA);
    gl2lds16(gA + stepR + k0, lA + 2048);
    gl2lds16(gB + k0, lB);
    gl2lds16(gB + stepR + k0, lB + 2048);
    __syncthreads();
    short8 af[4], bfr[4];
#pragma unroll
    for (int t = 0; t < 4; ++t)
      af[t] = *(const short8*)&As[(wr + (t << 4) + fr) * 32 + fq];
#pragma unroll
    for (int t = 0; t < 4; ++t)
      bfr[t] = *(const short8*)&Bs[(wc + (t << 4) + fr) * 32 + fq];
#pragma unroll
    for (int i = 0; i < 4; ++i)
#pragma unroll
      for (int j = 0; j < 4; ++j)
        acc[i][j] = mfma_bf16(af[i], bfr[j], acc[i][j]);
    __syncthreads();
  }
  const int er = (lane >> 4) << 2, ec = lane & 15;
#pragma unroll
  for (int i = 0; i < 4; ++i)
#pragma unroll
    for (int j = 0; j < 4; ++j)
#pragma unroll
      for (int r = 0; r < 4; ++r) {
        long row = bm + wr + (i << 4) + er + r;
        long col = bn + wc + (j << 4) + ec;
        if (outbf) Cb[row * N + col] = f2b(acc[i][j][r]);
        else       Cf[row * N + col] = acc[i][j][r];
      }
}

// ---------------- beta = sigmoid(hs @ Wb) , fp32 ----------------
__global__ void k_beta(const float* __restrict__ hs, const float* __restrict__ Wb,
                       float* __restrict__ beta) {
  int t = blockIdx.x, tid = threadIdx.x;
  int h = tid >> 4, il = tid & 15;
  float s = 0.f;
  for (int i = il; i < 2048; i += 16) s += hs[(size_t)t * 2048 + i] * Wb[i * 16 + h];
  s += __shfl_down(s, 8, 16);
  s += __shfl_down(s, 4, 16);
  s += __shfl_down(s, 2, 16);
  s += __shfl_down(s, 1, 16);
  if (il == 0) beta[t * 16 + h] = 1.f / (1.f + __expf(-s));
}

// ---------------- causal conv(K=4) + SiLU + (l2norm for q,k) ----------------
// qkv bf16 [T][6144] (q|k|v). out: qn/kn/vn bf16 [H][T][128]
__global__ void k_conv(const u16* __restrict__ qkv,
                       const float* __restrict__ cwq, const float* __restrict__ cwk,
                       const float* __restrict__ cwv,
                       u16* __restrict__ qn, u16* __restrict__ kn, u16* __restrict__ vn) {
  int t = blockIdx.x, s = blockIdx.y;
  int kind = s >> 4, h = s & 15, d = threadIdx.x;
  int col = kind * 2048 + (h << 7) + d;
  const float* cw = (kind == 0) ? cwq : ((kind == 1) ? cwk : cwv);
  float4 w = *(const float4*)(cw + (size_t)((h << 7) + d) * 4);
  float x[4];
#pragma unroll
  for (int j = 0; j < 4; ++j) {
    int tt = t - 3 + j;
    x[j] = (tt >= 0) ? b2f(qkv[(size_t)tt * 6144 + col]) : 0.f;
  }
  float y = x[0] * w.x + x[1] * w.y + x[2] * w.z + x[3] * w.w;
  y = y / (1.f + __expf(-y));  // SiLU
  float sc = 1.f;
  __shared__ float red[2];
  if (kind < 2) {
    float ss = y * y;
#pragma unroll
    for (int off = 32; off; off >>= 1) ss += __shfl_down(ss, off, 64);
    int lane = threadIdx.x & 63, wv = threadIdx.x >> 6;
    if (lane == 0) red[wv] = ss;
    __syncthreads();
    float tot = red[0] + red[1];
    sc = rsqrtf(tot + 1e-6f);
    if (kind == 0) sc *= 0.08838834764831843f;  // 128^-0.5
  }
  u16* dst = (kind == 0) ? qn : ((kind == 1) ? kn : vn);
  dst[((size_t)h << 18) + ((size_t)t << 7) + d] = f2b(y * sc);
}

// ---------------- per-(chunk,head): Tmat = (I + strict_tril(b*KK^T))^-1, G = tril(QK^T) ----------------
__global__ __launch_bounds__(256, 1)
void k_prep(const u16* __restrict__ qn, const u16* __restrict__ kn,
            const float* __restrict__ beta, u16* __restrict__ Tm, u16* __restrict__ Gm) {
  __shared__ __align__(16) u16 Kc[64 * 136];
  __shared__ __align__(16) u16 Qc[64 * 136];
  __shared__ float AL[64 * 68];
  __shared__ float TT[64 * 68];
  __shared__ float Bl[64];
  int h = blockIdx.x, c = blockIdx.y;
  int tid = threadIdx.x, wave = tid >> 6, lane = tid & 63;
  const u16* kb = kn + ((size_t)h << 18) + (size_t)c * 8192;
  const u16* qb = qn + ((size_t)h << 18) + (size_t)c * 8192;
#pragma unroll
  for (int s = 0; s < 4; ++s) {
    int e = (tid + (s << 8)) << 3;
    int t = e >> 7, d = e & 127;
    *(u16x8*)&Kc[t * 136 + d] = *(const u16x8*)(kb + e);
    *(u16x8*)&Qc[t * 136 + d] = *(const u16x8*)(qb + e);
  }
  if (tid < 64) Bl[tid] = beta[((c << 6) + tid) * 16 + h];
  __syncthreads();
  int fr = lane & 15, fq = (lane >> 4) << 3, q4 = (lane >> 4) << 2;
  int arow = (wave << 4) + fr;
  f32x4 kk[4], qk[4];
#pragma unroll
  for (int ct = 0; ct < 4; ++ct) { kk[ct] = (f32x4){0.f,0.f,0.f,0.f}; qk[ct] = (f32x4){0.f,0.f,0.f,0.f}; }
#pragma unroll
  for (int ks = 0; ks < 4; ++ks) {
    short8 aK = *(const short8*)&Kc[arow * 136 + (ks << 5) + fq];
    short8 aQ = *(const short8*)&Qc[arow * 136 + (ks << 5) + fq];
#pragma unroll
    for (int ct = 0; ct < 4; ++ct) {
      short8 bK = *(const short8*)&Kc[((ct << 4) + fr) * 136 + (ks << 5) + fq];
      kk[ct] = mfma_bf16(aK, bK, kk[ct]);
      qk[ct] = mfma_bf16(aQ, bK, qk[ct]);
    }
  }
  size_t gbase = ((size_t)(c * 16 + h)) << 12;
#pragma unroll
  for (int ct = 0; ct < 4; ++ct)
#pragma unroll
    for (int r = 0; r < 4; ++r) {
      int i = (wave << 4) + q4 + r, j = (ct << 4) + fr;
      AL[i * 68 + j] = (j < i) ? Bl[i] * kk[ct][r] : 0.f;
      Gm[gbase + i * 64 + j] = f2b((j <= i) ? qk[ct][r] : 0.f);
    }
  for (int e = tid; e < 64 * 68; e += 256) TT[e] = 0.f;
  __syncthreads();
  if (tid < 64) TT[tid * 68 + tid] = 1.f;
  __syncthreads();
  // forward substitution: T[i][j] = -sum_{l=j}^{i-1} A[i][l]*T[l][j]; TT holds T^T
  for (int i = 1; i < 64; ++i) {
    if (tid < i) {
      int j = tid;
      float s = 0.f;
      int l = j;
      for (; l < i && (l & 3); ++l) s += AL[i * 68 + l] * TT[j * 68 + l];
      for (; l + 4 <= i; l += 4) {
        float4 a4 = *(const float4*)&AL[i * 68 + l];
        float4 t4 = *(const float4*)&TT[j * 68 + l];
        s += a4.x * t4.x + a4.y * t4.y + a4.z * t4.z + a4.w * t4.w;
      }
      for (; l < i; ++l) s += AL[i * 68 + l] * TT[j * 68 + l];
      TT[j * 68 + i] = -s;
    }
    __syncthreads();
  }
  for (int e = tid; e < 4096; e += 256) {
    int i = e >> 6, j = e & 63;
    Tm[gbase + e] = f2b(TT[j * 68 + i]);
  }
}

// ---------------- sequential chunked delta-rule scan ----------------
// 64 blocks: h = bx>>2 (16 heads), v-slice = (bx&3)*32. State S^T[32][128] in MFMA acc regs.
__global__ __launch_bounds__(256, 1)
void k_delta(const u16* __restrict__ qn, const u16* __restrict__ kn, const u16* __restrict__ vn,
             const float* __restrict__ beta, const u16* __restrict__ Tm, const u16* __restrict__ Gm,
             float* __restrict__ o) {
  __shared__ __align__(16) u16 Kc[64 * 136];
  __shared__ __align__(16) u16 Qc[64 * 136];
  __shared__ __align__(16) u16 KT[128 * 72];
  __shared__ __align__(16) u16 Tc[64 * 72];
  __shared__ __align__(16) u16 Gc[64 * 72];
  __shared__ __align__(16) u16 Vs[64 * 40];
  __shared__ __align__(16) u16 ST[32 * 136];
  __shared__ __align__(16) u16 RT[32 * 72];
  __shared__ __align__(16) u16 DT[32 * 72];
  __shared__ float Bl[64];
  int bx = blockIdx.x;
  int h = bx >> 2, vbase = (bx & 3) << 5;
  int tid = threadIdx.x, wave = tid >> 6, lane = tid & 63;
  int fr = lane & 15, fq = (lane >> 4) << 3, q4 = (lane >> 4) << 2, wsd = wave << 5;
  const u16* kh = kn + ((size_t)h << 18);
  const u16* qh = qn + ((size_t)h << 18);
  const u16* vh = vn + ((size_t)h << 18);
  float* oh = o + ((size_t)h << 18);
  const f32x4 zero4 = {0.f, 0.f, 0.f, 0.f};
  f32x4 S[2][2];
#pragma unroll
  for (int a = 0; a < 2; ++a)
#pragma unroll
    for (int b = 0; b < 2; ++b) S[a][b] = zero4;
  int arow = (wave << 4) + fr;
  for (int c = 0; c < 32; ++c) {
    const u16* kb = kh + (size_t)c * 8192;
    const u16* qb = qh + (size_t)c * 8192;
#pragma unroll
    for (int s = 0; s < 4; ++s) {
      int e = (tid + (s << 8)) << 3;
      int t = e >> 7, d = e & 127;
      u16x8 vk = *(const u16x8*)(kb + e);
      *(u16x8*)&Kc[t * 136 + d] = vk;
#pragma unroll
      for (int i2 = 0; i2 < 8; ++i2) KT[(d + i2) * 72 + t] = vk[i2];
      *(u16x8*)&Qc[t * 136 + d] = *(const u16x8*)(qb + e);
    }
    {
      int e = tid << 3;
      int t = e >> 5, v = e & 31;
      *(u16x8*)&Vs[t * 40 + v] = *(const u16x8*)(vh + (size_t)((c << 6) + t) * 128 + vbase + v);
    }
    const u16* Tg = Tm + (((size_t)(c * 16 + h)) << 12);
    const u16* Gg = Gm + (((size_t)(c * 16 + h)) << 12);
#pragma unroll
    for (int s = 0; s < 2; ++s) {
      int e = (tid + (s << 8)) << 3;
      int i = e >> 6, l = e & 63;
      *(u16x8*)&Tc[i * 72 + l] = *(const u16x8*)(Tg + e);
      *(u16x8*)&Gc[i * 72 + l] = *(const u16x8*)(Gg + e);
    }
    if (tid < 64) Bl[tid] = beta[((c << 6) + tid) * 16 + h];
    // write S^T (bf16) into LDS for use as B-operand
#pragma unroll
    for (int vt = 0; vt < 2; ++vt)
#pragma unroll
      for (int dt = 0; dt < 2; ++dt)
#pragma unroll
        for (int r = 0; r < 4; ++r)
          ST[((vt << 4) + q4 + r) * 136 + wsd + (dt << 4) + fr] = f2b(S[vt][dt][r]);
    __syncthreads();
    // m1: R0 = K@S ; m1b: O0 = Q@S  (wave handles rows wave*16..+16)
    f32x4 racc[2] = {zero4, zero4}, oacc[2] = {zero4, zero4};
#pragma unroll
    for (int ks = 0; ks < 4; ++ks) {
      short8 aK = *(const short8*)&Kc[arow * 136 + (ks << 5) + fq];
      short8 aQ = *(const short8*)&Qc[arow * 136 + (ks << 5) + fq];
#pragma unroll
      for (int vt = 0; vt < 2; ++vt) {
        short8 bS = *(const short8*)&ST[((vt << 4) + fr) * 136 + (ks << 5) + fq];
        racc[vt] = mfma_bf16(aK, bS, racc[vt]);
        oacc[vt] = mfma_bf16(aQ, bS, oacc[vt]);
      }
    }
    // R = beta*(V - R0), write R^T
#pragma unroll
    for (int vt = 0; vt < 2; ++vt)
#pragma unroll
      for (int r = 0; r < 4; ++r) {
        int tl = (wave << 4) + q4 + r, v = (vt << 4) + fr;
        float Rv = Bl[tl] * (b2f(Vs[tl * 40 + v]) - racc[vt][r]);
        RT[v * 72 + tl] = f2b(Rv);
      }
    __syncthreads();
    // m2: Delta = Tmat @ R
    f32x4 dacc[2] = {zero4, zero4};
#pragma unroll
    for (int ks = 0; ks < 2; ++ks) {
      short8 aT = *(const short8*)&Tc[arow * 72 + (ks << 5) + fq];
#pragma unroll
      for (int vt = 0; vt < 2; ++vt) {
        short8 bR = *(const short8*)&RT[((vt << 4) + fr) * 72 + (ks << 5) + fq];
        dacc[vt] = mfma_bf16(aT, bR, dacc[vt]);
      }
    }
#pragma unroll
    for (int vt = 0; vt < 2; ++vt)
#pragma unroll
      for (int r = 0; r < 4; ++r)
        DT[((vt << 4) + fr) * 72 + (wave << 4) + q4 + r] = f2b(dacc[vt][r]);
    __syncthreads();
    // m2b: O = O0 + G @ Delta
#pragma unroll
    for (int ks = 0; ks < 2; ++ks) {
      short8 aG = *(const short8*)&Gc[arow * 72 + (ks << 5) + fq];
#pragma unroll
      for (int vt = 0; vt < 2; ++vt) {
        short8 bD = *(const short8*)&DT[((vt << 4) + fr) * 72 + (ks << 5) + fq];
        oacc[vt] = mfma_bf16(aG, bD, oacc[vt]);
      }
    }
#pragma unroll
    for (int vt = 0; vt < 2; ++vt)
#pragma unroll
      for (int r = 0; r < 4; ++r) {
        int tl = (wave << 4) + q4 + r;
        oh[(size_t)((c << 6) + tl) * 128 + vbase + (vt << 4) + fr] = oacc[vt][r];
      }
    // m3: S^T += Delta^T @ K   (wave handles d-cols wsd..wsd+32)
#pragma unroll
    for (int ks = 0; ks < 2; ++ks) {
      short8 aD[2];
#pragma unroll
      for (int vt = 0; vt < 2; ++vt)
        aD[vt] = *(const short8*)&DT[((vt << 4) + fr) * 72 + (ks << 5) + fq];
#pragma unroll
      for (int dt = 0; dt < 2; ++dt) {
        short8 bK = *(const short8*)&KT[(wsd + (dt << 4) + fr) * 72 + (ks << 5) + fq];
#pragma unroll
        for (int vt = 0; vt < 2; ++vt) S[vt][dt] = mfma_bf16(aD[vt], bK, S[vt][dt]);
      }
    }
    __syncthreads();
  }
}

// ---------------- per-head RMSNorm on o, emit bf16 [T][H*128] ----------------
__global__ void k_onorm(const float* __restrict__ o, const float* __restrict__ onw,
                        u16* __restrict__ onb) {
  int t = blockIdx.x, h = blockIdx.y, d = threadIdx.x;
  float x = o[((size_t)h << 18) + ((size_t)t << 7) + d];
  float ss = x * x;
#pragma unroll
  for (int off = 32; off; off >>= 1) ss += __shfl_down(ss, off, 64);
  __shared__ float red[2];
  int lane = d & 63, wv = d >> 6;
  if (lane == 0) red[wv] = ss;
  __syncthreads();
  float tot = red[0] + red[1];
  float y = x * rsqrtf(tot * (1.f / 128.f) + 1e-6f) * onw[d];
  onb[((size_t)t << 11) + (h << 7) + d] = f2b(y);
}

extern "C" void kernel_launch(void* const* d_in, const int* in_sizes, int n_in,
                              void* d_out, int out_size, void* d_ws, size_t ws_size,
                              hipStream_t stream) {
  (void)in_sizes; (void)n_in; (void)out_size; (void)ws_size;
  const float* hs  = (const float*)d_in[0];
  const float* Wq  = (const float*)d_in[1];
  const float* Wk  = (const float*)d_in[2];
  const float* Wv  = (const float*)d_in[3];
  const float* Wb  = (const float*)d_in[4];
  const float* cwq = (const float*)d_in[5];
  const float* cwk = (const float*)d_in[6];
  const float* cwv = (const float*)d_in[7];
  const float* onw = (const float*)d_in[8];
  const float* Wo  = (const float*)d_in[9];
  float* out = (float*)d_out;
  char* ws = (char*)d_ws;
  const size_t MB = 1ull << 20;
  u16*  Xb   = (u16*)(ws);              //  8 MB  hs bf16 [2048][2048]
  u16*  WT   = (u16*)(ws + 8  * MB);    // 24 MB  [Wq|Wk|Wv]^T bf16 [6144][2048]
  u16*  WoT  = (u16*)(ws + 32 * MB);    //  8 MB  Wo^T bf16
  u16*  QKV  = (u16*)(ws + 40 * MB);    // 24 MB  qkv pre-activations bf16 [2048][6144]
  u16*  qn_  = (u16*)(ws + 64 * MB);    //  8 MB  [16][2048][128]
  u16*  kn_  = (u16*)(ws + 72 * MB);    //  8 MB
  u16*  vn_  = (u16*)(ws + 80 * MB);    //  8 MB
  float* beta= (float*)(ws + 88 * MB);  //  128KB [2048][16]
  u16*  Tm   = (u16*)(ws + 89 * MB);    //  4 MB  [32][16][64][64]
  u16*  Gm   = (u16*)(ws + 93 * MB);    //  4 MB
  float* o_  = (float*)(ws + 97 * MB);  // 16 MB  [16][2048][128]
  u16*  onb  = (u16*)(ws + 113 * MB);   //  8 MB  [2048][2048]

  dim3 tb(32, 8);
  k_cvt<<<4096, 256, 0, stream>>>(hs, Xb, 2048 * 2048 / 4);
  k_transpose<<<dim3(64, 64), tb, 0, stream>>>(Wq, WT,                 2048, 2048);
  k_transpose<<<dim3(64, 64), tb, 0, stream>>>(Wk, WT + 2048 * 2048,   2048, 2048);
  k_transpose<<<dim3(64, 64), tb, 0, stream>>>(Wv, WT + 2 * 2048 * 2048, 2048, 2048);
  k_transpose<<<dim3(64, 64), tb, 0, stream>>>(Wo, WoT,                2048, 2048);
  k_gemm_bt<<<dim3(48, 16), 256, 0, stream>>>(Xb, WT, nullptr, QKV, 2048, 6144, 2048, 1);
  k_beta<<<2048, 256, 0, stream>>>(hs, Wb, beta);
  k_conv<<<dim3(2048, 48), 128, 0, stream>>>(QKV, cwq, cwk, cwv, qn_, kn_, vn_);
  k_prep<<<dim3(16, 32), 256, 0, stream>>>(qn_, kn_, beta, Tm, Gm);
  k_delta<<<64, 256, 0, stream>>>(qn_, kn_, vn_, beta, Tm, Gm, o_);
  k_onorm<<<dim3(2048, 16), 128, 0, stream>>>(o_, onw, onb);
  k_gemm_bt<<<dim3(16, 16), 256, 0, stream>>>(onb, WoT, out, nullptr, 2048, 2048, 2048, 0);
}

// Round 2
// 602.461 us; speedup vs baseline: 1.0144x; 1.0144x over previous
//
#include <hip/hip_runtime.h>

typedef unsigned short u16;
typedef __attribute__((ext_vector_type(4))) unsigned short u16x4;
typedef __attribute__((ext_vector_type(8))) unsigned short u16x8;
typedef __attribute__((ext_vector_type(8))) short short8;
typedef __attribute__((ext_vector_type(4))) float f32x4;

#define DEVI __device__ __forceinline__

DEVI u16 f2b(float f) {
  union { float f; unsigned u; } x; x.f = f;
  unsigned r = (x.u + 0x7fffu + ((x.u >> 16) & 1u)) >> 16;
  return (u16)r;
}
DEVI float b2f(u16 h) {
  union { unsigned u; float f; } x; x.u = ((unsigned)h) << 16;
  return x.f;
}
DEVI f32x4 mfma_bf16(short8 a, short8 b, f32x4 c) {
  return __builtin_amdgcn_mfma_f32_16x16x32_bf16(a, b, c, 0, 0, 0);
}
DEVI void gl2lds16(const u16* g, u16* l) {
  __builtin_amdgcn_global_load_lds((__attribute__((address_space(1))) void*)g,
                                   (__attribute__((address_space(3))) void*)l,
                                   16, 0, 0);
}
// barrier that drains only LDS (lgkmcnt), NOT vmcnt -> global prefetch stays in flight
DEVI void barrier_lds() {
  asm volatile("s_waitcnt lgkmcnt(0)\n\ts_barrier" ::: "memory");
}

// ---------------- fp32 -> bf16 convert (hidden_states) ----------------
__global__ void k_cvt(const float* __restrict__ src, u16* __restrict__ dst, int n4) {
  int i = blockIdx.x * 256 + threadIdx.x;
  if (i < n4) {
    float4 v = ((const float4*)src)[i];
    u16x4 r; r.x = f2b(v.x); r.y = f2b(v.y); r.z = f2b(v.z); r.w = f2b(v.w);
    ((u16x4*)dst)[i] = r;
  }
}

// ---------------- tiled transpose fp32[R][C] -> bf16[C][R] ----------------
__global__ void k_transpose(const float* __restrict__ src, u16* __restrict__ dst, int R, int C) {
  __shared__ float tile[32][33];
  int bx = blockIdx.x << 5, by = blockIdx.y << 5;
  int x = threadIdx.x, y = threadIdx.y;
#pragma unroll
  for (int j = 0; j < 32; j += 8)
    tile[y + j][x] = src[(size_t)(by + y + j) * C + bx + x];
  __syncthreads();
#pragma unroll
  for (int j = 0; j < 32; j += 8)
    dst[(size_t)(bx + y + j) * R + by + x] = f2b(tile[x][y + j]);
}

// ---------------- bf16 MFMA GEMM: C[M][N] = A[M][K] @ BT[N][K]^T ----------------
__global__ __launch_bounds__(256, 2)
void k_gemm_bt(const u16* __restrict__ A, const u16* __restrict__ BT,
               float* __restrict__ Cf, u16* __restrict__ Cb,
               int M, int N, int K, int outbf) {
  __shared__ __align__(16) u16 As[4096];
  __shared__ __align__(16) u16 Bs[4096];
  const int tid = threadIdx.x, wave = tid >> 6, lane = tid & 63;
  const long bm = (long)blockIdx.y << 7, bn = (long)blockIdx.x << 7;
  const int r0 = (wave << 4) + (lane >> 2), kof = (lane & 3) << 3;
  const u16* gA = A + (bm + r0) * (long)K + kof;
  const u16* gB = BT + (bn + r0) * (long)K + kof;
  u16* lA = As + (wave << 9);
  u16* lB = Bs + (wave << 9);
  const long stepR = (long)64 * K;
  const int wr = (wave >> 1) << 6, wc = (wave & 1) << 6;
  const int fr = lane & 15, fq = (lane >> 4) << 3;
  f32x4 acc[4][4];
#pragma unroll
  for (int i = 0; i < 4; ++i)
#pragma unroll
    for (int j = 0; j < 4; ++j) acc[i][j] = (f32x4){0.f, 0.f, 0.f, 0.f};
  for (int k0 = 0; k0 < K; k0 += 32) {
    gl2lds16(gA + k0, lA);
    gl2lds16(gA + stepR + k0, lA + 2048);
    gl2lds16(gB + k0, lB);
    gl2lds16(gB + stepR + k0, lB + 2048);
    __syncthreads();
    short8 af[4], bfr[4];
#pragma unroll
    for (int t = 0; t < 4; ++t)
      af[t] = *(const short8*)&As[(wr + (t << 4) + fr) * 32 + fq];
#pragma unroll
    for (int t = 0; t < 4; ++t)
      bfr[t] = *(const short8*)&Bs[(wc + (t << 4) + fr) * 32 + fq];
#pragma unroll
    for (int i = 0; i < 4; ++i)
#pragma unroll
      for (int j = 0; j < 4; ++j)
        acc[i][j] = mfma_bf16(af[i], bfr[j], acc[i][j]);
    __syncthreads();
  }
  const int er = (lane >> 4) << 2, ec = lane & 15;
#pragma unroll
  for (int i = 0; i < 4; ++i)
#pragma unroll
    for (int j = 0; j < 4; ++j)
#pragma unroll
      for (int r = 0; r < 4; ++r) {
        long row = bm + wr + (i << 4) + er + r;
        long col = bn + wc + (j << 4) + ec;
        if (outbf) Cb[row * N + col] = f2b(acc[i][j][r]);
        else       Cf[row * N + col] = acc[i][j][r];
      }
}

// ---------------- beta = sigmoid(hs @ Wb) , fp32 ----------------
__global__ void k_beta(const float* __restrict__ hs, const float* __restrict__ Wb,
                       float* __restrict__ beta) {
  int t = blockIdx.x, tid = threadIdx.x;
  int h = tid >> 4, il = tid & 15;
  float s = 0.f;
  for (int i = il; i < 2048; i += 16) s += hs[(size_t)t * 2048 + i] * Wb[i * 16 + h];
  s += __shfl_down(s, 8, 16);
  s += __shfl_down(s, 4, 16);
  s += __shfl_down(s, 2, 16);
  s += __shfl_down(s, 1, 16);
  if (il == 0) beta[t * 16 + h] = 1.f / (1.f + __expf(-s));
}

// ---------------- causal conv(K=4) + SiLU + (l2norm for q,k) ----------------
__global__ void k_conv(const u16* __restrict__ qkv,
                       const float* __restrict__ cwq, const float* __restrict__ cwk,
                       const float* __restrict__ cwv,
                       u16* __restrict__ qn, u16* __restrict__ kn, u16* __restrict__ vn) {
  int t = blockIdx.x, s = blockIdx.y;
  int kind = s >> 4, h = s & 15, d = threadIdx.x;
  int col = kind * 2048 + (h << 7) + d;
  const float* cw = (kind == 0) ? cwq : ((kind == 1) ? cwk : cwv);
  float4 w = *(const float4*)(cw + (size_t)((h << 7) + d) * 4);
  float x[4];
#pragma unroll
  for (int j = 0; j < 4; ++j) {
    int tt = t - 3 + j;
    x[j] = (tt >= 0) ? b2f(qkv[(size_t)tt * 6144 + col]) : 0.f;
  }
  float y = x[0] * w.x + x[1] * w.y + x[2] * w.z + x[3] * w.w;
  y = y / (1.f + __expf(-y));  // SiLU
  float sc = 1.f;
  __shared__ float red[2];
  if (kind < 2) {
    float ss = y * y;
#pragma unroll
    for (int off = 32; off; off >>= 1) ss += __shfl_down(ss, off, 64);
    int lane = threadIdx.x & 63, wv = threadIdx.x >> 6;
    if (lane == 0) red[wv] = ss;
    __syncthreads();
    float tot = red[0] + red[1];
    sc = rsqrtf(tot + 1e-6f);
    if (kind == 0) sc *= 0.08838834764831843f;  // 128^-0.5
  }
  u16* dst = (kind == 0) ? qn : ((kind == 1) ? kn : vn);
  dst[((size_t)h << 18) + ((size_t)t << 7) + d] = f2b(y * sc);
}

// ---------------- per-(chunk,head) parallel prep ----------------
// Outputs: Gg = tril(QK^T) [ch][64][64]; Wg = T'K [ch][64][128];
//          KTg = K^T [ch][128][64]; UTg = (T'V)^T [ch][128][64]   (T' = (I+A)^-1 diag(beta))
__global__ __launch_bounds__(256, 1)
void k_prep(const u16* __restrict__ qn, const u16* __restrict__ kn, const u16* __restrict__ vn,
            const float* __restrict__ beta,
            u16* __restrict__ Gg, u16* __restrict__ Wg,
            u16* __restrict__ KTg, u16* __restrict__ UTg) {
  __shared__ __align__(16) char sm[133888];
  u16*  Kc  = (u16*)sm;                 // 64*136*2 = 17408
  u16*  Qc  = (u16*)(sm + 17408);       // 17408 (reused later to stage W)
  u16*  Vc  = (u16*)(sm + 34816);       // 17408
  u16*  KTl = (u16*)(sm + 52224);       // 128*72*2 = 18432
  u16*  VTl = (u16*)(sm + 70656);       // 18432
  float* AL = (float*)(sm + 89088);     // 64*68*4 = 17408
  float* TT = (float*)(sm + 106496);    // 17408
  u16*  UT  = (u16*)(sm + 89088);       // reuse AL..TT after fwdsub: 128*72*2
  u16*  Tb  = (u16*)(sm + 123904);      // 64*72*2 = 9216
  float* Bl = (float*)(sm + 133120);    // 256
  int h = blockIdx.x, c = blockIdx.y;
  int tid = threadIdx.x, wave = tid >> 6, lane = tid & 63;
  size_t ch = (size_t)(c * 16 + h);
  const u16* kb = kn + ((size_t)h << 18) + ((size_t)c << 13);
  const u16* qb = qn + ((size_t)h << 18) + ((size_t)c << 13);
  const u16* vb = vn + ((size_t)h << 18) + ((size_t)c << 13);
#pragma unroll
  for (int s = 0; s < 4; ++s) {
    int e = (tid + (s << 8)) << 3;
    int t = e >> 7, d = e & 127;
    *(u16x8*)&Kc[t * 136 + d] = *(const u16x8*)(kb + e);
    *(u16x8*)&Qc[t * 136 + d] = *(const u16x8*)(qb + e);
    *(u16x8*)&Vc[t * 136 + d] = *(const u16x8*)(vb + e);
  }
  if (tid < 64) Bl[tid] = beta[((c << 6) + tid) * 16 + h];
  __syncthreads();
  // transpose K,V into KTl/VTl; stream K^T to global
  {
    int d = tid & 127, tg = tid >> 7;
#pragma unroll
    for (int it = 0; it < 4; ++it) {
      int t0 = (tg + (it << 1)) << 3;
      u16x8 pk, pv;
#pragma unroll
      for (int j = 0; j < 8; ++j) {
        pk[j] = Kc[(t0 + j) * 136 + d];
        pv[j] = Vc[(t0 + j) * 136 + d];
      }
      *(u16x8*)&KTl[d * 72 + t0] = pk;
      *(u16x8*)&VTl[d * 72 + t0] = pv;
      *(u16x8*)(KTg + (ch << 13) + (d << 6) + t0) = pk;
    }
  }
  int fr = lane & 15, fq = (lane >> 4) << 3, q4 = (lane >> 4) << 2;
  int arow = (wave << 4) + fr;
  f32x4 kk[4], qk[4];
#pragma unroll
  for (int ct = 0; ct < 4; ++ct) { kk[ct] = (f32x4){0.f,0.f,0.f,0.f}; qk[ct] = (f32x4){0.f,0.f,0.f,0.f}; }
#pragma unroll
  for (int ks = 0; ks < 4; ++ks) {
    short8 aK = *(const short8*)&Kc[arow * 136 + (ks << 5) + fq];
    short8 aQ = *(const short8*)&Qc[arow * 136 + (ks << 5) + fq];
#pragma unroll
    for (int ct = 0; ct < 4; ++ct) {
      short8 bK = *(const short8*)&Kc[((ct << 4) + fr) * 136 + (ks << 5) + fq];
      kk[ct] = mfma_bf16(aK, bK, kk[ct]);
      qk[ct] = mfma_bf16(aQ, bK, qk[ct]);
    }
  }
#pragma unroll
  for (int ct = 0; ct < 4; ++ct)
#pragma unroll
    for (int r = 0; r < 4; ++r) {
      int i = (wave << 4) + q4 + r, j = (ct << 4) + fr;
      AL[i * 68 + j] = (j < i) ? Bl[i] * kk[ct][r] : 0.f;
      Gg[(ch << 12) + i * 64 + j] = f2b((j <= i) ? qk[ct][r] : 0.f);
    }
  for (int e = tid; e < 64 * 68; e += 256) TT[e] = 0.f;
  __syncthreads();
  if (tid < 64) TT[tid * 68 + tid] = 1.f;
  __syncthreads();
  // forward substitution: T = (I+A)^-1, TT[j][i] = T[i][j]
  for (int i = 1; i < 64; ++i) {
    if (tid < i) {
      int j = tid;
      float s = 0.f;
      int l = j;
      for (; l < i && (l & 3); ++l) s += AL[i * 68 + l] * TT[j * 68 + l];
      for (; l + 4 <= i; l += 4) {
        float4 a4 = *(const float4*)&AL[i * 68 + l];
        float4 t4 = *(const float4*)&TT[j * 68 + l];
        s += a4.x * t4.x + a4.y * t4.y + a4.z * t4.z + a4.w * t4.w;
      }
      for (; l < i; ++l) s += AL[i * 68 + l] * TT[j * 68 + l];
      TT[j * 68 + i] = -s;
    }
    __syncthreads();
  }
  // Tb[i][l] = T[i][l] * beta[l]
  for (int e = tid; e < 4096; e += 256) {
    int i = e & 63, l = e >> 6;
    Tb[i * 72 + l] = f2b(TT[l * 68 + i] * Bl[l]);
  }
  __syncthreads();
  // W = Tb @ K  (B = K^T), U = Tb @ V (B = V^T)
  short8 aT[2];
#pragma unroll
  for (int ks = 0; ks < 2; ++ks) aT[ks] = *(const short8*)&Tb[arow * 72 + (ks << 5) + fq];
  f32x4 wacc[8], uacc[8];
#pragma unroll
  for (int d = 0; d < 8; ++d) { wacc[d] = (f32x4){0.f,0.f,0.f,0.f}; uacc[d] = (f32x4){0.f,0.f,0.f,0.f}; }
#pragma unroll
  for (int ks = 0; ks < 2; ++ks)
#pragma unroll
    for (int dt = 0; dt < 8; ++dt) {
      short8 bK = *(const short8*)&KTl[((dt << 4) + fr) * 72 + (ks << 5) + fq];
      short8 bV = *(const short8*)&VTl[((dt << 4) + fr) * 72 + (ks << 5) + fq];
      wacc[dt] = mfma_bf16(aT[ks], bK, wacc[dt]);
      uacc[dt] = mfma_bf16(aT[ks], bV, uacc[dt]);
    }
  // stage W into Qc (row-major), U into UT (transposed)
#pragma unroll
  for (int dt = 0; dt < 8; ++dt)
#pragma unroll
    for (int r = 0; r < 4; ++r) {
      int i = (wave << 4) + q4 + r, dcol = (dt << 4) + fr;
      Qc[i * 136 + dcol] = f2b(wacc[dt][r]);
      UT[dcol * 72 + i] = f2b(uacc[dt][r]);
    }
  __syncthreads();
  // coalesced global writes
#pragma unroll
  for (int it = 0; it < 4; ++it) {
    int e = tid + (it << 8);
    int t = e >> 4, d0 = (e & 15) << 3;
    *(u16x8*)(Wg + (ch << 13) + (t << 7) + d0) = *(const u16x8*)&Qc[t * 136 + d0];
    int v = e >> 3, t0 = (e & 7) << 3;
    *(u16x8*)(UTg + (ch << 13) + (v << 6) + t0) = *(const u16x8*)&UT[v * 72 + t0];
  }
}

// ---------------- sequential chunked delta-rule scan (lean) ----------------
// 128 blocks: h = bx&15, v-slice = (bx>>4)*16. Per chunk:
//   Delta = U - W*S ; O = Q*S + G*Delta ; S += K^T Delta
// All chunk-constant fragments stream global->VGPR, prefetched 1 chunk ahead.
struct Frags { short8 q[4], w[4], g[2], k[4]; u16x4 u; };

DEVI void load_frags(Frags& f, const u16* qh, const u16* Wg, const u16* Gg,
                     const u16* KTg, const u16* UTg, int c, int h,
                     int trow, int fr, int fq, int q4, int w, int vbase) {
  const u16* qb = qh + ((size_t)((c << 6) + trow + fr) << 7) + fq;
#pragma unroll
  for (int ks = 0; ks < 4; ++ks) f.q[ks] = *(const short8*)(qb + (ks << 5));
  size_t ch = (size_t)(c * 16 + h);
  const u16* wb = Wg + (ch << 13) + ((size_t)(trow + fr) << 7) + fq;
#pragma unroll
  for (int ks = 0; ks < 4; ++ks) f.w[ks] = *(const short8*)(wb + (ks << 5));
  const u16* gb = Gg + (ch << 12) + ((size_t)(trow + fr) << 6) + fq;
#pragma unroll
  for (int ks = 0; ks < 2; ++ks) f.g[ks] = *(const short8*)(gb + (ks << 5));
  const u16* kbp = KTg + (ch << 13) + ((size_t)(w << 5) << 6) + fq;
#pragma unroll
  for (int dt = 0; dt < 2; ++dt)
#pragma unroll
    for (int ks = 0; ks < 2; ++ks)
      f.k[(dt << 1) | ks] = *(const short8*)(kbp + ((size_t)((dt << 4) + fr) << 6) + (ks << 5));
  f.u = *(const u16x4*)(UTg + (ch << 13) + ((size_t)(vbase + fr) << 6) + trow + q4);
}

DEVI void chunk_body(int c, Frags& f, u16* ST, u16* DT, float* oh,
                     int trow, int fr, int fq, int q4, int w, int vbase,
                     f32x4& S0, f32x4& S1) {
  // publish S^T (this wave's 32 d-columns)
#pragma unroll
  for (int r = 0; r < 4; ++r) {
    ST[(q4 + r) * 136 + (w << 5) + fr] = f2b(S0[r]);
    ST[(q4 + r) * 136 + (w << 5) + 16 + fr] = f2b(S1[r]);
  }
  barrier_lds();
  short8 sf[4];
#pragma unroll
  for (int ks = 0; ks < 4; ++ks) sf[ks] = *(const short8*)&ST[fr * 136 + (ks << 5) + fq];
  f32x4 racc = {0.f,0.f,0.f,0.f}, oacc = {0.f,0.f,0.f,0.f};
#pragma unroll
  for (int ks = 0; ks < 4; ++ks) {
    racc = mfma_bf16(f.w[ks], sf[ks], racc);
    oacc = mfma_bf16(f.q[ks], sf[ks], oacc);
  }
  // Delta = U - W*S, publish Delta^T
#pragma unroll
  for (int r = 0; r < 4; ++r)
    DT[fr * 72 + trow + q4 + r] = f2b(b2f(f.u[r]) - racc[r]);
  barrier_lds();
  short8 df[2];
#pragma unroll
  for (int ks = 0; ks < 2; ++ks) df[ks] = *(const short8*)&DT[fr * 72 + (ks << 5) + fq];
#pragma unroll
  for (int ks = 0; ks < 2; ++ks) {
    oacc = mfma_bf16(f.g[ks], df[ks], oacc);
    S0 = mfma_bf16(df[ks], f.k[ks], S0);
    S1 = mfma_bf16(df[ks], f.k[2 | ks], S1);
  }
#pragma unroll
  for (int r = 0; r < 4; ++r)
    oh[(size_t)((c << 6) + trow + q4 + r) * 128 + vbase + fr] = oacc[r];
}

__global__ __launch_bounds__(256, 1)
void k_delta(const u16* __restrict__ qn, const u16* __restrict__ Wg,
             const u16* __restrict__ Gg, const u16* __restrict__ KTg,
             const u16* __restrict__ UTg, float* __restrict__ o) {
  __shared__ __align__(16) u16 ST[16 * 136];
  __shared__ __align__(16) u16 DT[16 * 72];
  int bx = blockIdx.x;
  int h = bx & 15, vbase = (bx >> 4) << 4;
  int tid = threadIdx.x, w = tid >> 6, lane = tid & 63;
  int fr = lane & 15, fq = (lane >> 4) << 3, q4 = (lane >> 4) << 2;
  int trow = w << 4;
  const u16* qh = qn + ((size_t)h << 18);
  float* oh = o + ((size_t)h << 18);
  f32x4 S0 = {0.f,0.f,0.f,0.f}, S1 = {0.f,0.f,0.f,0.f};
  Frags fa, fb;
  load_frags(fa, qh, Wg, Gg, KTg, UTg, 0, h, trow, fr, fq, q4, w, vbase);
  for (int c = 0; c < 32; c += 2) {
    int c1 = c + 1, c2 = (c + 2 < 32) ? c + 2 : 31;
    load_frags(fb, qh, Wg, Gg, KTg, UTg, c1, h, trow, fr, fq, q4, w, vbase);
    chunk_body(c, fa, ST, DT, oh, trow, fr, fq, q4, w, vbase, S0, S1);
    load_frags(fa, qh, Wg, Gg, KTg, UTg, c2, h, trow, fr, fq, q4, w, vbase);
    chunk_body(c1, fb, ST, DT, oh, trow, fr, fq, q4, w, vbase, S0, S1);
  }
}

// ---------------- per-head RMSNorm on o, emit bf16 [T][H*128] ----------------
__global__ void k_onorm(const float* __restrict__ o, const float* __restrict__ onw,
                        u16* __restrict__ onb) {
  int t = blockIdx.x, h = blockIdx.y, d = threadIdx.x;
  float x = o[((size_t)h << 18) + ((size_t)t << 7) + d];
  float ss = x * x;
#pragma unroll
  for (int off = 32; off; off >>= 1) ss += __shfl_down(ss, off, 64);
  __shared__ float red[2];
  int lane = d & 63, wv = d >> 6;
  if (lane == 0) red[wv] = ss;
  __syncthreads();
  float tot = red[0] + red[1];
  float y = x * rsqrtf(tot * (1.f / 128.f) + 1e-6f) * onw[d];
  onb[((size_t)t << 11) + (h << 7) + d] = f2b(y);
}

extern "C" void kernel_launch(void* const* d_in, const int* in_sizes, int n_in,
                              void* d_out, int out_size, void* d_ws, size_t ws_size,
                              hipStream_t stream) {
  (void)in_sizes; (void)n_in; (void)out_size; (void)ws_size;
  const float* hs  = (const float*)d_in[0];
  const float* Wq  = (const float*)d_in[1];
  const float* Wk  = (const float*)d_in[2];
  const float* Wv  = (const float*)d_in[3];
  const float* Wb  = (const float*)d_in[4];
  const float* cwq = (const float*)d_in[5];
  const float* cwk = (const float*)d_in[6];
  const float* cwv = (const float*)d_in[7];
  const float* onw = (const float*)d_in[8];
  const float* Wo  = (const float*)d_in[9];
  float* out = (float*)d_out;
  char* ws = (char*)d_ws;
  const size_t MB = 1ull << 20;
  u16*  Xb   = (u16*)(ws);              //  8 MB  hs bf16 [2048][2048]
  u16*  WT   = (u16*)(ws + 8  * MB);    // 24 MB  [Wq|Wk|Wv]^T bf16 [6144][2048]
  u16*  WoT  = (u16*)(ws + 32 * MB);    //  8 MB  Wo^T bf16
  u16*  QKV  = (u16*)(ws + 40 * MB);    // 24 MB  qkv pre-activations (dead after k_conv)
  u16*  Wg   = (u16*)(ws + 40 * MB);    //  8 MB  overlays dead QKV
  u16*  KTg  = (u16*)(ws + 48 * MB);    //  8 MB
  u16*  UTg  = (u16*)(ws + 56 * MB);    //  8 MB
  u16*  qn_  = (u16*)(ws + 64 * MB);    //  8 MB  [16][2048][128]
  u16*  kn_  = (u16*)(ws + 72 * MB);    //  8 MB
  u16*  vn_  = (u16*)(ws + 80 * MB);    //  8 MB
  float* beta= (float*)(ws + 88 * MB);  //  128KB [2048][16]
  u16*  Gm   = (u16*)(ws + 89 * MB);    //  4 MB  [32*16][64][64]
  float* o_  = (float*)(ws + 93 * MB);  // 16 MB  [16][2048][128]
  u16*  onb  = (u16*)(ws + 109 * MB);   //  8 MB  [2048][2048]

  dim3 tb(32, 8);
  k_cvt<<<4096, 256, 0, stream>>>(hs, Xb, 2048 * 2048 / 4);
  k_transpose<<<dim3(64, 64), tb, 0, stream>>>(Wq, WT,                   2048, 2048);
  k_transpose<<<dim3(64, 64), tb, 0, stream>>>(Wk, WT + 2048 * 2048,     2048, 2048);
  k_transpose<<<dim3(64, 64), tb, 0, stream>>>(Wv, WT + 2 * 2048 * 2048, 2048, 2048);
  k_transpose<<<dim3(64, 64), tb, 0, stream>>>(Wo, WoT,                  2048, 2048);
  k_gemm_bt<<<dim3(48, 16), 256, 0, stream>>>(Xb, WT, nullptr, QKV, 2048, 6144, 2048, 1);
  k_beta<<<2048, 256, 0, stream>>>(hs, Wb, beta);
  k_conv<<<dim3(2048, 48), 128, 0, stream>>>(QKV, cwq, cwk, cwv, qn_, kn_, vn_);
  k_prep<<<dim3(16, 32), 256, 0, stream>>>(qn_, kn_, vn_, beta, Gm, Wg, KTg, UTg);
  k_delta<<<128, 256, 0, stream>>>(qn_, Wg, Gm, KTg, UTg, o_);
  k_onorm<<<dim3(2048, 16), 128, 0, stream>>>(o_, onw, onb);
  k_gemm_bt<<<dim3(16, 16), 256, 0, stream>>>(onb, WoT, out, nullptr, 2048, 2048, 2048, 0);
}

// Round 3
// 511.422 us; speedup vs baseline: 1.1950x; 1.1780x over previous
//
#include <hip/hip_runtime.h>

typedef unsigned short u16;
typedef __attribute__((ext_vector_type(4))) unsigned short u16x4;
typedef __attribute__((ext_vector_type(8))) unsigned short u16x8;
typedef __attribute__((ext_vector_type(8))) short short8;
typedef __attribute__((ext_vector_type(4))) float f32x4;

#define DEVI __device__ __forceinline__

DEVI u16 f2b(float f) {
  union { float f; unsigned u; } x; x.f = f;
  unsigned r = (x.u + 0x7fffu + ((x.u >> 16) & 1u)) >> 16;
  return (u16)r;
}
DEVI float b2f(u16 h) {
  union { unsigned u; float f; } x; x.u = ((unsigned)h) << 16;
  return x.f;
}
DEVI f32x4 mfma_bf16(short8 a, short8 b, f32x4 c) {
  return __builtin_amdgcn_mfma_f32_16x16x32_bf16(a, b, c, 0, 0, 0);
}
DEVI void gl2lds16(const u16* g, u16* l) {
  __builtin_amdgcn_global_load_lds((__attribute__((address_space(1))) void*)g,
                                   (__attribute__((address_space(3))) void*)l,
                                   16, 0, 0);
}
// barrier that drains only LDS (lgkmcnt), NOT vmcnt -> global prefetch stays in flight
DEVI void barrier_lds() {
  asm volatile("s_waitcnt lgkmcnt(0)\n\ts_barrier" ::: "memory");
}

// ---------------- fp32 -> bf16 convert (hidden_states) ----------------
__global__ void k_cvt(const float* __restrict__ src, u16* __restrict__ dst, int n4) {
  int i = blockIdx.x * 256 + threadIdx.x;
  if (i < n4) {
    float4 v = ((const float4*)src)[i];
    u16x4 r; r.x = f2b(v.x); r.y = f2b(v.y); r.z = f2b(v.z); r.w = f2b(v.w);
    ((u16x4*)dst)[i] = r;
  }
}

// ---------------- tiled transpose fp32[R][C] -> bf16[C][R] ----------------
__global__ void k_transpose(const float* __restrict__ src, u16* __restrict__ dst, int R, int C) {
  __shared__ float tile[32][33];
  int bx = blockIdx.x << 5, by = blockIdx.y << 5;
  int x = threadIdx.x, y = threadIdx.y;
#pragma unroll
  for (int j = 0; j < 32; j += 8)
    tile[y + j][x] = src[(size_t)(by + y + j) * C + bx + x];
  __syncthreads();
#pragma unroll
  for (int j = 0; j < 32; j += 8)
    dst[(size_t)(bx + y + j) * R + by + x] = f2b(tile[x][y + j]);
}

// ---------------- bf16 MFMA GEMM: C[M][N] = A[M][K] @ BT[N][K]^T ----------------
__global__ __launch_bounds__(256, 2)
void k_gemm_bt(const u16* __restrict__ A, const u16* __restrict__ BT,
               float* __restrict__ Cf, u16* __restrict__ Cb,
               int M, int N, int K, int outbf) {
  __shared__ __align__(16) u16 As[4096];
  __shared__ __align__(16) u16 Bs[4096];
  const int tid = threadIdx.x, wave = tid >> 6, lane = tid & 63;
  const long bm = (long)blockIdx.y << 7, bn = (long)blockIdx.x << 7;
  const int r0 = (wave << 4) + (lane >> 2), kof = (lane & 3) << 3;
  const u16* gA = A + (bm + r0) * (long)K + kof;
  const u16* gB = BT + (bn + r0) * (long)K + kof;
  u16* lA = As + (wave << 9);
  u16* lB = Bs + (wave << 9);
  const long stepR = (long)64 * K;
  const int wr = (wave >> 1) << 6, wc = (wave & 1) << 6;
  const int fr = lane & 15, fq = (lane >> 4) << 3;
  f32x4 acc[4][4];
#pragma unroll
  for (int i = 0; i < 4; ++i)
#pragma unroll
    for (int j = 0; j < 4; ++j) acc[i][j] = (f32x4){0.f, 0.f, 0.f, 0.f};
  for (int k0 = 0; k0 < K; k0 += 32) {
    gl2lds16(gA + k0, lA);
    gl2lds16(gA + stepR + k0, lA + 2048);
    gl2lds16(gB + k0, lB);
    gl2lds16(gB + stepR + k0, lB + 2048);
    __syncthreads();
    short8 af[4], bfr[4];
#pragma unroll
    for (int t = 0; t < 4; ++t)
      af[t] = *(const short8*)&As[(wr + (t << 4) + fr) * 32 + fq];
#pragma unroll
    for (int t = 0; t < 4; ++t)
      bfr[t] = *(const short8*)&Bs[(wc + (t << 4) + fr) * 32 + fq];
#pragma unroll
    for (int i = 0; i < 4; ++i)
#pragma unroll
      for (int j = 0; j < 4; ++j)
        acc[i][j] = mfma_bf16(af[i], bfr[j], acc[i][j]);
    __syncthreads();
  }
  const int er = (lane >> 4) << 2, ec = lane & 15;
#pragma unroll
  for (int i = 0; i < 4; ++i)
#pragma unroll
    for (int j = 0; j < 4; ++j)
#pragma unroll
      for (int r = 0; r < 4; ++r) {
        long row = bm + wr + (i << 4) + er + r;
        long col = bn + wc + (j << 4) + ec;
        if (outbf) Cb[row * N + col] = f2b(acc[i][j][r]);
        else       Cf[row * N + col] = acc[i][j][r];
      }
}

// ---------------- beta = sigmoid(hs @ Wb) , fp32 ----------------
__global__ void k_beta(const float* __restrict__ hs, const float* __restrict__ Wb,
                       float* __restrict__ beta) {
  int t = blockIdx.x, tid = threadIdx.x;
  int h = tid >> 4, il = tid & 15;
  float s = 0.f;
  for (int i = il; i < 2048; i += 16) s += hs[(size_t)t * 2048 + i] * Wb[i * 16 + h];
  s += __shfl_down(s, 8, 16);
  s += __shfl_down(s, 4, 16);
  s += __shfl_down(s, 2, 16);
  s += __shfl_down(s, 1, 16);
  if (il == 0) beta[t * 16 + h] = 1.f / (1.f + __expf(-s));
}

// ---------------- causal conv(K=4) + SiLU + (l2norm for q,k) ----------------
__global__ void k_conv(const u16* __restrict__ qkv,
                       const float* __restrict__ cwq, const float* __restrict__ cwk,
                       const float* __restrict__ cwv,
                       u16* __restrict__ qn, u16* __restrict__ kn, u16* __restrict__ vn) {
  int t = blockIdx.x, s = blockIdx.y;
  int kind = s >> 4, h = s & 15, d = threadIdx.x;
  int col = kind * 2048 + (h << 7) + d;
  const float* cw = (kind == 0) ? cwq : ((kind == 1) ? cwk : cwv);
  float4 w = *(const float4*)(cw + (size_t)((h << 7) + d) * 4);
  float x[4];
#pragma unroll
  for (int j = 0; j < 4; ++j) {
    int tt = t - 3 + j;
    x[j] = (tt >= 0) ? b2f(qkv[(size_t)tt * 6144 + col]) : 0.f;
  }
  float y = x[0] * w.x + x[1] * w.y + x[2] * w.z + x[3] * w.w;
  y = y / (1.f + __expf(-y));  // SiLU
  float sc = 1.f;
  __shared__ float red[2];
  if (kind < 2) {
    float ss = y * y;
#pragma unroll
    for (int off = 32; off; off >>= 1) ss += __shfl_down(ss, off, 64);
    int lane = threadIdx.x & 63, wv = threadIdx.x >> 6;
    if (lane == 0) red[wv] = ss;
    __syncthreads();
    float tot = red[0] + red[1];
    sc = rsqrtf(tot + 1e-6f);
    if (kind == 0) sc *= 0.08838834764831843f;  // 128^-0.5
  }
  u16* dst = (kind == 0) ? qn : ((kind == 1) ? kn : vn);
  dst[((size_t)h << 18) + ((size_t)t << 7) + d] = f2b(y * sc);
}

// ---------------- per-(chunk,head) parallel prep (v3) ----------------
// Outputs: Gg = tril(QK^T); KTg = K^T; Wg = T'K; UTg = (T'V)^T, T' = (I+A)^-1 diag(beta)
// Solve done per-thread-column (256 cols = 128 K + 128 V), X in VGPRs, A broadcast from LDS.
__global__ __launch_bounds__(256, 2)
void k_prep(const u16* __restrict__ qn, const u16* __restrict__ kn, const u16* __restrict__ vn,
            const float* __restrict__ beta,
            u16* __restrict__ Gg, u16* __restrict__ Wg,
            u16* __restrict__ KTg, u16* __restrict__ UTg) {
  __shared__ __align__(16) char sm[70912];
  u16*  Kc  = (u16*)sm;                 // 64*136*2 = 17408
  u16*  Qc  = (u16*)(sm + 17408);       // 17408 ; overlay: WR (64*136*2)
  u16*  Vc  = (u16*)(sm + 34816);       // 17408
  u16*  KTl = (u16*)(sm + 52224);       // 128*72*2 = 18432 ; overlay: AL (64*64*4)
  float* AL = (float*)(sm + 52224);
  float* Bl = (float*)(sm + 70656);     // 256
  u16*  WR  = Qc;
  int h = blockIdx.x, c = blockIdx.y;
  int tid = threadIdx.x, wave = tid >> 6, lane = tid & 63;
  size_t ch = (size_t)(c * 16 + h);
  const u16* kb = kn + ((size_t)h << 18) + ((size_t)c << 13);
  const u16* qb = qn + ((size_t)h << 18) + ((size_t)c << 13);
  const u16* vb = vn + ((size_t)h << 18) + ((size_t)c << 13);
#pragma unroll
  for (int s = 0; s < 4; ++s) {
    int e = (tid + (s << 8)) << 3;
    int t = e >> 7, d = e & 127;
    *(u16x8*)&Kc[t * 136 + d] = *(const u16x8*)(kb + e);
    *(u16x8*)&Qc[t * 136 + d] = *(const u16x8*)(qb + e);
    *(u16x8*)&Vc[t * 136 + d] = *(const u16x8*)(vb + e);
  }
  if (tid < 64) Bl[tid] = beta[((c << 6) + tid) * 16 + h];
  __syncthreads();
  // MFMA: kk = K K^T, qk = Q K^T  (wave handles rows wave*16..+16)
  int fr = lane & 15, fq = (lane >> 4) << 3, q4 = (lane >> 4) << 2;
  int arow = (wave << 4) + fr;
  f32x4 kk[4], qk[4];
#pragma unroll
  for (int ct = 0; ct < 4; ++ct) { kk[ct] = (f32x4){0.f,0.f,0.f,0.f}; qk[ct] = (f32x4){0.f,0.f,0.f,0.f}; }
#pragma unroll
  for (int ks = 0; ks < 4; ++ks) {
    short8 aK = *(const short8*)&Kc[arow * 136 + (ks << 5) + fq];
    short8 aQ = *(const short8*)&Qc[arow * 136 + (ks << 5) + fq];
#pragma unroll
    for (int ct = 0; ct < 4; ++ct) {
      short8 bK = *(const short8*)&Kc[((ct << 4) + fr) * 136 + (ks << 5) + fq];
      kk[ct] = mfma_bf16(aK, bK, kk[ct]);
      qk[ct] = mfma_bf16(aQ, bK, qk[ct]);
    }
  }
  // G = tril(QK^T) -> global
#pragma unroll
  for (int ct = 0; ct < 4; ++ct)
#pragma unroll
    for (int r = 0; r < 4; ++r) {
      int i = (wave << 4) + q4 + r, j = (ct << 4) + fr;
      Gg[(ch << 12) + i * 64 + j] = f2b((j <= i) ? qk[ct][r] : 0.f);
    }
  // K^T into KTl (scalar transpose reads)
  {
    int d = tid & 127, tg = tid >> 7;
#pragma unroll
    for (int it = 0; it < 4; ++it) {
      int t0 = (tg + (it << 1)) << 3;
      u16x8 pk;
#pragma unroll
      for (int j = 0; j < 8; ++j) pk[j] = Kc[(t0 + j) * 136 + d];
      *(u16x8*)&KTl[d * 72 + t0] = pk;
    }
  }
  __syncthreads();
  // flush KTl -> KTg, coalesced 16B chunks
#pragma unroll
  for (int it = 0; it < 4; ++it) {
    int idx = tid + (it << 8);          // 0..1023
    int row = idx >> 3, j8 = (idx & 7) << 3;
    *(u16x8*)(KTg + (ch << 13) + (row << 6) + j8) = *(const u16x8*)&KTl[row * 72 + j8];
  }
  __syncthreads();
  // AL[i][j] = (j<i) ? beta[i]*kk[i][j] : 0   (overlays KTl)
  {
    float bi[4];
#pragma unroll
    for (int r = 0; r < 4; ++r) bi[r] = Bl[(wave << 4) + q4 + r];
#pragma unroll
    for (int ct = 0; ct < 4; ++ct)
#pragma unroll
      for (int r = 0; r < 4; ++r) {
        int i = (wave << 4) + q4 + r, j = (ct << 4) + fr;
        AL[i * 64 + j] = (j < i) ? bi[r] * kk[ct][r] : 0.f;
      }
  }
  __syncthreads();
  // per-thread-column triangular solve: X[r] = beta[r]*B[r] - sum_{l<r} AL[r][l] X[l]
  float X[64];
  {
    const u16* colp = (tid < 128) ? (Kc + tid) : (Vc + (tid - 128));
#pragma unroll
    for (int t = 0; t < 64; ++t) X[t] = Bl[t] * b2f(colp[t * 136]);
#pragma unroll
    for (int r = 1; r < 64; ++r) {
      float s = 0.f;
      const float* Ar = &AL[r * 64];
      int r4 = r & ~3;
#pragma unroll
      for (int l = 0; l < 64; l += 4)
        if (l + 4 <= r) {
          float4 a = *(const float4*)(Ar + l);
          s += a.x * X[l] + a.y * X[l + 1] + a.z * X[l + 2] + a.w * X[l + 3];
        }
#pragma unroll
      for (int l = 0; l < 4; ++l)
        if (r4 + l < r) s += Ar[r4 + l] * X[r4 + l];
      X[r] -= s;
    }
  }
  __syncthreads();   // Qc dead -> WR overlay
  if (tid < 128) {
    // stage W columns: WR[t][c] (row stride 136)
#pragma unroll
    for (int t = 0; t < 64; ++t) WR[t * 136 + tid] = f2b(X[t]);
  } else {
    // UT row v = X: contiguous 128B per thread, direct global
    int v = tid - 128;
    u16* dstr = UTg + (ch << 13) + (v << 6);
#pragma unroll
    for (int j = 0; j < 8; ++j) {
      u16x8 p;
#pragma unroll
      for (int e = 0; e < 8; ++e) p[e] = f2b(X[(j << 3) + e]);
      *(u16x8*)(dstr + (j << 3)) = p;
    }
  }
  __syncthreads();
  // flush WR -> Wg, coalesced: 64 rows x 128 cols = 1024 chunks of 8
#pragma unroll
  for (int it = 0; it < 4; ++it) {
    int idx = tid + (it << 8);          // 0..1023
    int row = idx >> 4, j8 = (idx & 15) << 3;
    *(u16x8*)(Wg + (ch << 13) + (row << 7) + j8) = *(const u16x8*)&WR[row * 136 + j8];
  }
}

// ---------------- sequential chunked delta-rule scan (lean) ----------------
// 128 blocks: h = bx&15, v-slice = (bx>>4)*16. Per chunk:
//   Delta = U - W*S ; O = Q*S + G*Delta ; S += K^T Delta
// All chunk-constant fragments stream global->VGPR, prefetched 1 chunk ahead.
struct Frags { short8 q[4], w[4], g[2], k[4]; u16x4 u; };

DEVI void load_frags(Frags& f, const u16* qh, const u16* Wg, const u16* Gg,
                     const u16* KTg, const u16* UTg, int c, int h,
                     int trow, int fr, int fq, int q4, int w, int vbase) {
  const u16* qb = qh + ((size_t)((c << 6) + trow + fr) << 7) + fq;
#pragma unroll
  for (int ks = 0; ks < 4; ++ks) f.q[ks] = *(const short8*)(qb + (ks << 5));
  size_t ch = (size_t)(c * 16 + h);
  const u16* wb = Wg + (ch << 13) + ((size_t)(trow + fr) << 7) + fq;
#pragma unroll
  for (int ks = 0; ks < 4; ++ks) f.w[ks] = *(const short8*)(wb + (ks << 5));
  const u16* gb = Gg + (ch << 12) + ((size_t)(trow + fr) << 6) + fq;
#pragma unroll
  for (int ks = 0; ks < 2; ++ks) f.g[ks] = *(const short8*)(gb + (ks << 5));
  const u16* kbp = KTg + (ch << 13) + ((size_t)(w << 5) << 6) + fq;
#pragma unroll
  for (int dt = 0; dt < 2; ++dt)
#pragma unroll
    for (int ks = 0; ks < 2; ++ks)
      f.k[(dt << 1) | ks] = *(const short8*)(kbp + ((size_t)((dt << 4) + fr) << 6) + (ks << 5));
  f.u = *(const u16x4*)(UTg + (ch << 13) + ((size_t)(vbase + fr) << 6) + trow + q4);
}

DEVI void chunk_body(int c, Frags& f, u16* ST, u16* DT, float* oh,
                     int trow, int fr, int fq, int q4, int w, int vbase,
                     f32x4& S0, f32x4& S1) {
  // publish S^T (this wave's 32 d-columns)
#pragma unroll
  for (int r = 0; r < 4; ++r) {
    ST[(q4 + r) * 136 + (w << 5) + fr] = f2b(S0[r]);
    ST[(q4 + r) * 136 + (w << 5) + 16 + fr] = f2b(S1[r]);
  }
  barrier_lds();
  short8 sf[4];
#pragma unroll
  for (int ks = 0; ks < 4; ++ks) sf[ks] = *(const short8*)&ST[fr * 136 + (ks << 5) + fq];
  f32x4 racc = {0.f,0.f,0.f,0.f}, oacc = {0.f,0.f,0.f,0.f};
#pragma unroll
  for (int ks = 0; ks < 4; ++ks) {
    racc = mfma_bf16(f.w[ks], sf[ks], racc);
    oacc = mfma_bf16(f.q[ks], sf[ks], oacc);
  }
  // Delta = U - W*S, publish Delta^T
#pragma unroll
  for (int r = 0; r < 4; ++r)
    DT[fr * 72 + trow + q4 + r] = f2b(b2f(f.u[r]) - racc[r]);
  barrier_lds();
  short8 df[2];
#pragma unroll
  for (int ks = 0; ks < 2; ++ks) df[ks] = *(const short8*)&DT[fr * 72 + (ks << 5) + fq];
#pragma unroll
  for (int ks = 0; ks < 2; ++ks) {
    oacc = mfma_bf16(f.g[ks], df[ks], oacc);
    S0 = mfma_bf16(df[ks], f.k[ks], S0);
    S1 = mfma_bf16(df[ks], f.k[2 | ks], S1);
  }
#pragma unroll
  for (int r = 0; r < 4; ++r)
    oh[(size_t)((c << 6) + trow + q4 + r) * 128 + vbase + fr] = oacc[r];
}

__global__ __launch_bounds__(256, 1)
void k_delta(const u16* __restrict__ qn, const u16* __restrict__ Wg,
             const u16* __restrict__ Gg, const u16* __restrict__ KTg,
             const u16* __restrict__ UTg, float* __restrict__ o) {
  __shared__ __align__(16) u16 ST[16 * 136];
  __shared__ __align__(16) u16 DT[16 * 72];
  int bx = blockIdx.x;
  int h = bx & 15, vbase = (bx >> 4) << 4;
  int tid = threadIdx.x, w = tid >> 6, lane = tid & 63;
  int fr = lane & 15, fq = (lane >> 4) << 3, q4 = (lane >> 4) << 2;
  int trow = w << 4;
  const u16* qh = qn + ((size_t)h << 18);
  float* oh = o + ((size_t)h << 18);
  f32x4 S0 = {0.f,0.f,0.f,0.f}, S1 = {0.f,0.f,0.f,0.f};
  Frags fa, fb;
  load_frags(fa, qh, Wg, Gg, KTg, UTg, 0, h, trow, fr, fq, q4, w, vbase);
  for (int c = 0; c < 32; c += 2) {
    int c1 = c + 1, c2 = (c + 2 < 32) ? c + 2 : 31;
    load_frags(fb, qh, Wg, Gg, KTg, UTg, c1, h, trow, fr, fq, q4, w, vbase);
    chunk_body(c, fa, ST, DT, oh, trow, fr, fq, q4, w, vbase, S0, S1);
    load_frags(fa, qh, Wg, Gg, KTg, UTg, c2, h, trow, fr, fq, q4, w, vbase);
    chunk_body(c1, fb, ST, DT, oh, trow, fr, fq, q4, w, vbase, S0, S1);
  }
}

// ---------------- per-head RMSNorm on o, emit bf16 [T][H*128] ----------------
__global__ void k_onorm(const float* __restrict__ o, const float* __restrict__ onw,
                        u16* __restrict__ onb) {
  int t = blockIdx.x, h = blockIdx.y, d = threadIdx.x;
  float x = o[((size_t)h << 18) + ((size_t)t << 7) + d];
  float ss = x * x;
#pragma unroll
  for (int off = 32; off; off >>= 1) ss += __shfl_down(ss, off, 64);
  __shared__ float red[2];
  int lane = d & 63, wv = d >> 6;
  if (lane == 0) red[wv] = ss;
  __syncthreads();
  float tot = red[0] + red[1];
  float y = x * rsqrtf(tot * (1.f / 128.f) + 1e-6f) * onw[d];
  onb[((size_t)t << 11) + (h << 7) + d] = f2b(y);
}

extern "C" void kernel_launch(void* const* d_in, const int* in_sizes, int n_in,
                              void* d_out, int out_size, void* d_ws, size_t ws_size,
                              hipStream_t stream) {
  (void)in_sizes; (void)n_in; (void)out_size; (void)ws_size;
  const float* hs  = (const float*)d_in[0];
  const float* Wq  = (const float*)d_in[1];
  const float* Wk  = (const float*)d_in[2];
  const float* Wv  = (const float*)d_in[3];
  const float* Wb  = (const float*)d_in[4];
  const float* cwq = (const float*)d_in[5];
  const float* cwk = (const float*)d_in[6];
  const float* cwv = (const float*)d_in[7];
  const float* onw = (const float*)d_in[8];
  const float* Wo  = (const float*)d_in[9];
  float* out = (float*)d_out;
  char* ws = (char*)d_ws;
  const size_t MB = 1ull << 20;
  u16*  Xb   = (u16*)(ws);              //  8 MB  hs bf16 [2048][2048]
  u16*  WT   = (u16*)(ws + 8  * MB);    // 24 MB  [Wq|Wk|Wv]^T bf16 [6144][2048]
  u16*  WoT  = (u16*)(ws + 32 * MB);    //  8 MB  Wo^T bf16
  u16*  QKV  = (u16*)(ws + 40 * MB);    // 24 MB  qkv pre-activations (dead after k_conv)
  u16*  Wg   = (u16*)(ws + 40 * MB);    //  8 MB  overlays dead QKV
  u16*  KTg  = (u16*)(ws + 48 * MB);    //  8 MB
  u16*  UTg  = (u16*)(ws + 56 * MB);    //  8 MB
  u16*  qn_  = (u16*)(ws + 64 * MB);    //  8 MB  [16][2048][128]
  u16*  kn_  = (u16*)(ws + 72 * MB);    //  8 MB
  u16*  vn_  = (u16*)(ws + 80 * MB);    //  8 MB
  float* beta= (float*)(ws + 88 * MB);  //  128KB [2048][16]
  u16*  Gm   = (u16*)(ws + 89 * MB);    //  4 MB  [32*16][64][64]
  float* o_  = (float*)(ws + 93 * MB);  // 16 MB  [16][2048][128]
  u16*  onb  = (u16*)(ws + 109 * MB);   //  8 MB  [2048][2048]

  dim3 tb(32, 8);
  k_cvt<<<4096, 256, 0, stream>>>(hs, Xb, 2048 * 2048 / 4);
  k_transpose<<<dim3(64, 64), tb, 0, stream>>>(Wq, WT,                   2048, 2048);
  k_transpose<<<dim3(64, 64), tb, 0, stream>>>(Wk, WT + 2048 * 2048,     2048, 2048);
  k_transpose<<<dim3(64, 64), tb, 0, stream>>>(Wv, WT + 2 * 2048 * 2048, 2048, 2048);
  k_transpose<<<dim3(64, 64), tb, 0, stream>>>(Wo, WoT,                  2048, 2048);
  k_gemm_bt<<<dim3(48, 16), 256, 0, stream>>>(Xb, WT, nullptr, QKV, 2048, 6144, 2048, 1);
  k_beta<<<2048, 256, 0, stream>>>(hs, Wb, beta);
  k_conv<<<dim3(2048, 48), 128, 0, stream>>>(QKV, cwq, cwk, cwv, qn_, kn_, vn_);
  k_prep<<<dim3(16, 32), 256, 0, stream>>>(qn_, kn_, vn_, beta, Gm, Wg, KTg, UTg);
  k_delta<<<128, 256, 0, stream>>>(qn_, Wg, Gm, KTg, UTg, o_);
  k_onorm<<<dim3(2048, 16), 128, 0, stream>>>(o_, onw, onb);
  k_gemm_bt<<<dim3(16, 16), 256, 0, stream>>>(onb, WoT, out, nullptr, 2048, 2048, 2048, 0);
}

// Round 4
// 399.580 us; speedup vs baseline: 1.5295x; 1.2799x over previous
//
#include <hip/hip_runtime.h>

typedef unsigned short u16;
typedef __attribute__((ext_vector_type(4))) unsigned short u16x4;
typedef __attribute__((ext_vector_type(8))) unsigned short u16x8;
typedef __attribute__((ext_vector_type(8))) short short8;
typedef __attribute__((ext_vector_type(4))) float f32x4;

#define DEVI __device__ __forceinline__

DEVI u16 f2b(float f) {
  union { float f; unsigned u; } x; x.f = f;
  unsigned r = (x.u + 0x7fffu + ((x.u >> 16) & 1u)) >> 16;
  return (u16)r;
}
DEVI float b2f(u16 h) {
  union { unsigned u; float f; } x; x.u = ((unsigned)h) << 16;
  return x.f;
}
DEVI f32x4 mfma_bf16(short8 a, short8 b, f32x4 c) {
  return __builtin_amdgcn_mfma_f32_16x16x32_bf16(a, b, c, 0, 0, 0);
}
DEVI void gl2lds16(const u16* g, u16* l) {
  __builtin_amdgcn_global_load_lds((__attribute__((address_space(1))) void*)g,
                                   (__attribute__((address_space(3))) void*)l,
                                   16, 0, 0);
}
// barrier that drains only LDS (lgkmcnt), NOT vmcnt -> global prefetch stays in flight
DEVI void barrier_lds() {
  asm volatile("s_waitcnt lgkmcnt(0)\n\ts_barrier" ::: "memory");
}

// ---------------- fp32 -> bf16 convert (hidden_states) ----------------
__global__ void k_cvt(const float* __restrict__ src, u16* __restrict__ dst, int n4) {
  int i = blockIdx.x * 256 + threadIdx.x;
  if (i < n4) {
    float4 v = ((const float4*)src)[i];
    u16x4 r; r.x = f2b(v.x); r.y = f2b(v.y); r.z = f2b(v.z); r.w = f2b(v.w);
    ((u16x4*)dst)[i] = r;
  }
}

// ---------------- tiled transpose fp32[R][C] -> bf16[C][R] ----------------
__global__ void k_transpose(const float* __restrict__ src, u16* __restrict__ dst, int R, int C) {
  __shared__ float tile[32][33];
  int bx = blockIdx.x << 5, by = blockIdx.y << 5;
  int x = threadIdx.x, y = threadIdx.y;
#pragma unroll
  for (int j = 0; j < 32; j += 8)
    tile[y + j][x] = src[(size_t)(by + y + j) * C + bx + x];
  __syncthreads();
#pragma unroll
  for (int j = 0; j < 32; j += 8)
    dst[(size_t)(bx + y + j) * R + by + x] = f2b(tile[x][y + j]);
}

// ---------------- bf16 MFMA GEMM: C[M][N] = A[M][K] @ BT[N][K]^T ----------------
__global__ __launch_bounds__(256, 2)
void k_gemm_bt(const u16* __restrict__ A, const u16* __restrict__ BT,
               float* __restrict__ Cf, u16* __restrict__ Cb,
               int M, int N, int K, int outbf) {
  __shared__ __align__(16) u16 As[4096];
  __shared__ __align__(16) u16 Bs[4096];
  const int tid = threadIdx.x, wave = tid >> 6, lane = tid & 63;
  const long bm = (long)blockIdx.y << 7, bn = (long)blockIdx.x << 7;
  const int r0 = (wave << 4) + (lane >> 2), kof = (lane & 3) << 3;
  const u16* gA = A + (bm + r0) * (long)K + kof;
  const u16* gB = BT + (bn + r0) * (long)K + kof;
  u16* lA = As + (wave << 9);
  u16* lB = Bs + (wave << 9);
  const long stepR = (long)64 * K;
  const int wr = (wave >> 1) << 6, wc = (wave & 1) << 6;
  const int fr = lane & 15, fq = (lane >> 4) << 3;
  f32x4 acc[4][4];
#pragma unroll
  for (int i = 0; i < 4; ++i)
#pragma unroll
    for (int j = 0; j < 4; ++j) acc[i][j] = (f32x4){0.f, 0.f, 0.f, 0.f};
  for (int k0 = 0; k0 < K; k0 += 32) {
    gl2lds16(gA + k0, lA);
    gl2lds16(gA + stepR + k0, lA + 2048);
    gl2lds16(gB + k0, lB);
    gl2lds16(gB + stepR + k0, lB + 2048);
    __syncthreads();
    short8 af[4], bfr[4];
#pragma unroll
    for (int t = 0; t < 4; ++t)
      af[t] = *(const short8*)&As[(wr + (t << 4) + fr) * 32 + fq];
#pragma unroll
    for (int t = 0; t < 4; ++t)
      bfr[t] = *(const short8*)&Bs[(wc + (t << 4) + fr) * 32 + fq];
#pragma unroll
    for (int i = 0; i < 4; ++i)
#pragma unroll
      for (int j = 0; j < 4; ++j)
        acc[i][j] = mfma_bf16(af[i], bfr[j], acc[i][j]);
    __syncthreads();
  }
  const int er = (lane >> 4) << 2, ec = lane & 15;
#pragma unroll
  for (int i = 0; i < 4; ++i)
#pragma unroll
    for (int j = 0; j < 4; ++j)
#pragma unroll
      for (int r = 0; r < 4; ++r) {
        long row = bm + wr + (i << 4) + er + r;
        long col = bn + wc + (j << 4) + ec;
        if (outbf) Cb[row * N + col] = f2b(acc[i][j][r]);
        else       Cf[row * N + col] = acc[i][j][r];
      }
}

// ---------------- Wb [2048][16] fp32 -> WbT [16][2048] bf16 (B-operand layout) ----------------
__global__ void k_wbT(const float* __restrict__ src, u16* __restrict__ dst) {
  int j = blockIdx.x * 256 + threadIdx.x;   // 0..32767
  int n = j >> 11, k = j & 2047;
  dst[j] = f2b(src[k * 16 + n]);
}

// ---------------- beta = sigmoid(hs @ Wb) via MFMA ----------------
// 128 blocks; block owns 16 rows; wave w owns K-slice [w*512,(w+1)*512)
__global__ __launch_bounds__(256, 4)
void k_beta(const u16* __restrict__ Xb, const u16* __restrict__ WbT,
            float* __restrict__ beta) {
  __shared__ float part[4][256];
  int tid = threadIdx.x, w = tid >> 6, lane = tid & 63;
  int t0 = blockIdx.x << 4;
  int fr = lane & 15, fq = (lane >> 4) << 3;
  const u16* ap = Xb + (size_t)(t0 + fr) * 2048 + (w << 9) + fq;
  const u16* bp = WbT + (size_t)fr * 2048 + (w << 9) + fq;
  f32x4 acc = {0.f, 0.f, 0.f, 0.f};
#pragma unroll
  for (int ks = 0; ks < 16; ++ks)
    acc = mfma_bf16(*(const short8*)(ap + (ks << 5)), *(const short8*)(bp + (ks << 5)), acc);
  int er = (lane >> 4) << 2;
#pragma unroll
  for (int r = 0; r < 4; ++r) part[w][(er + r) * 16 + fr] = acc[r];
  __syncthreads();
  float s = part[0][tid] + part[1][tid] + part[2][tid] + part[3][tid];
  beta[(t0 << 4) + tid] = 1.f / (1.f + __expf(-s));
}

// ---------------- causal conv(K=4) + SiLU + (l2norm for q,k) ----------------
__global__ void k_conv(const u16* __restrict__ qkv,
                       const float* __restrict__ cwq, const float* __restrict__ cwk,
                       const float* __restrict__ cwv,
                       u16* __restrict__ qn, u16* __restrict__ kn, u16* __restrict__ vn) {
  int t = blockIdx.x, s = blockIdx.y;
  int kind = s >> 4, h = s & 15, d = threadIdx.x;
  int col = kind * 2048 + (h << 7) + d;
  const float* cw = (kind == 0) ? cwq : ((kind == 1) ? cwk : cwv);
  float4 w = *(const float4*)(cw + (size_t)((h << 7) + d) * 4);
  float x[4];
#pragma unroll
  for (int j = 0; j < 4; ++j) {
    int tt = t - 3 + j;
    x[j] = (tt >= 0) ? b2f(qkv[(size_t)tt * 6144 + col]) : 0.f;
  }
  float y = x[0] * w.x + x[1] * w.y + x[2] * w.z + x[3] * w.w;
  y = y / (1.f + __expf(-y));  // SiLU
  float sc = 1.f;
  __shared__ float red[2];
  if (kind < 2) {
    float ss = y * y;
#pragma unroll
    for (int off = 32; off; off >>= 1) ss += __shfl_down(ss, off, 64);
    int lane = threadIdx.x & 63, wv = threadIdx.x >> 6;
    if (lane == 0) red[wv] = ss;
    __syncthreads();
    float tot = red[0] + red[1];
    sc = rsqrtf(tot + 1e-6f);
    if (kind == 0) sc *= 0.08838834764831843f;  // 128^-0.5
  }
  u16* dst = (kind == 0) ? qn : ((kind == 1) ? kn : vn);
  dst[((size_t)h << 18) + ((size_t)t << 7) + d] = f2b(y * sc);
}

// ---------------- per-(chunk,head) parallel prep (v3) ----------------
// Outputs: Gg = tril(QK^T); KTg = K^T; Wg = T'K; UTg = (T'V)^T, T' = (I+A)^-1 diag(beta)
// Solve done per-thread-column (256 cols = 128 K + 128 V), X in VGPRs, A broadcast from LDS.
__global__ __launch_bounds__(256, 2)
void k_prep(const u16* __restrict__ qn, const u16* __restrict__ kn, const u16* __restrict__ vn,
            const float* __restrict__ beta,
            u16* __restrict__ Gg, u16* __restrict__ Wg,
            u16* __restrict__ KTg, u16* __restrict__ UTg) {
  __shared__ __align__(16) char sm[70912];
  u16*  Kc  = (u16*)sm;                 // 64*136*2 = 17408
  u16*  Qc  = (u16*)(sm + 17408);       // 17408 ; overlay: WR (64*136*2)
  u16*  Vc  = (u16*)(sm + 34816);       // 17408
  u16*  KTl = (u16*)(sm + 52224);       // 128*72*2 = 18432 ; overlay: AL (64*64*4)
  float* AL = (float*)(sm + 52224);
  float* Bl = (float*)(sm + 70656);     // 256
  u16*  WR  = Qc;
  int h = blockIdx.x, c = blockIdx.y;
  int tid = threadIdx.x, wave = tid >> 6, lane = tid & 63;
  size_t ch = (size_t)(c * 16 + h);
  const u16* kb = kn + ((size_t)h << 18) + ((size_t)c << 13);
  const u16* qb = qn + ((size_t)h << 18) + ((size_t)c << 13);
  const u16* vb = vn + ((size_t)h << 18) + ((size_t)c << 13);
#pragma unroll
  for (int s = 0; s < 4; ++s) {
    int e = (tid + (s << 8)) << 3;
    int t = e >> 7, d = e & 127;
    *(u16x8*)&Kc[t * 136 + d] = *(const u16x8*)(kb + e);
    *(u16x8*)&Qc[t * 136 + d] = *(const u16x8*)(qb + e);
    *(u16x8*)&Vc[t * 136 + d] = *(const u16x8*)(vb + e);
  }
  if (tid < 64) Bl[tid] = beta[((c << 6) + tid) * 16 + h];
  __syncthreads();
  // MFMA: kk = K K^T, qk = Q K^T  (wave handles rows wave*16..+16)
  int fr = lane & 15, fq = (lane >> 4) << 3, q4 = (lane >> 4) << 2;
  int arow = (wave << 4) + fr;
  f32x4 kk[4], qk[4];
#pragma unroll
  for (int ct = 0; ct < 4; ++ct) { kk[ct] = (f32x4){0.f,0.f,0.f,0.f}; qk[ct] = (f32x4){0.f,0.f,0.f,0.f}; }
#pragma unroll
  for (int ks = 0; ks < 4; ++ks) {
    short8 aK = *(const short8*)&Kc[arow * 136 + (ks << 5) + fq];
    short8 aQ = *(const short8*)&Qc[arow * 136 + (ks << 5) + fq];
#pragma unroll
    for (int ct = 0; ct < 4; ++ct) {
      short8 bK = *(const short8*)&Kc[((ct << 4) + fr) * 136 + (ks << 5) + fq];
      kk[ct] = mfma_bf16(aK, bK, kk[ct]);
      qk[ct] = mfma_bf16(aQ, bK, qk[ct]);
    }
  }
  // G = tril(QK^T) -> global
#pragma unroll
  for (int ct = 0; ct < 4; ++ct)
#pragma unroll
    for (int r = 0; r < 4; ++r) {
      int i = (wave << 4) + q4 + r, j = (ct << 4) + fr;
      Gg[(ch << 12) + i * 64 + j] = f2b((j <= i) ? qk[ct][r] : 0.f);
    }
  // K^T into KTl (scalar transpose reads)
  {
    int d = tid & 127, tg = tid >> 7;
#pragma unroll
    for (int it = 0; it < 4; ++it) {
      int t0 = (tg + (it << 1)) << 3;
      u16x8 pk;
#pragma unroll
      for (int j = 0; j < 8; ++j) pk[j] = Kc[(t0 + j) * 136 + d];
      *(u16x8*)&KTl[d * 72 + t0] = pk;
    }
  }
  __syncthreads();
  // flush KTl -> KTg, coalesced 16B chunks
#pragma unroll
  for (int it = 0; it < 4; ++it) {
    int idx = tid + (it << 8);          // 0..1023
    int row = idx >> 3, j8 = (idx & 7) << 3;
    *(u16x8*)(KTg + (ch << 13) + (row << 6) + j8) = *(const u16x8*)&KTl[row * 72 + j8];
  }
  __syncthreads();
  // AL[i][j] = (j<i) ? beta[i]*kk[i][j] : 0   (overlays KTl)
  {
    float bi[4];
#pragma unroll
    for (int r = 0; r < 4; ++r) bi[r] = Bl[(wave << 4) + q4 + r];
#pragma unroll
    for (int ct = 0; ct < 4; ++ct)
#pragma unroll
      for (int r = 0; r < 4; ++r) {
        int i = (wave << 4) + q4 + r, j = (ct << 4) + fr;
        AL[i * 64 + j] = (j < i) ? bi[r] * kk[ct][r] : 0.f;
      }
  }
  __syncthreads();
  // per-thread-column triangular solve: X[r] = beta[r]*B[r] - sum_{l<r} AL[r][l] X[l]
  float X[64];
  {
    const u16* colp = (tid < 128) ? (Kc + tid) : (Vc + (tid - 128));
#pragma unroll
    for (int t = 0; t < 64; ++t) X[t] = Bl[t] * b2f(colp[t * 136]);
#pragma unroll
    for (int r = 1; r < 64; ++r) {
      float s = 0.f;
      const float* Ar = &AL[r * 64];
      int r4 = r & ~3;
#pragma unroll
      for (int l = 0; l < 64; l += 4)
        if (l + 4 <= r) {
          float4 a = *(const float4*)(Ar + l);
          s += a.x * X[l] + a.y * X[l + 1] + a.z * X[l + 2] + a.w * X[l + 3];
        }
#pragma unroll
      for (int l = 0; l < 4; ++l)
        if (r4 + l < r) s += Ar[r4 + l] * X[r4 + l];
      X[r] -= s;
    }
  }
  __syncthreads();   // Qc dead -> WR overlay
  if (tid < 128) {
    // stage W columns: WR[t][c] (row stride 136)
#pragma unroll
    for (int t = 0; t < 64; ++t) WR[t * 136 + tid] = f2b(X[t]);
  } else {
    // UT row v = X: contiguous 128B per thread, direct global
    int v = tid - 128;
    u16* dstr = UTg + (ch << 13) + (v << 6);
#pragma unroll
    for (int j = 0; j < 8; ++j) {
      u16x8 p;
#pragma unroll
      for (int e = 0; e < 8; ++e) p[e] = f2b(X[(j << 3) + e]);
      *(u16x8*)(dstr + (j << 3)) = p;
    }
  }
  __syncthreads();
  // flush WR -> Wg, coalesced: 64 rows x 128 cols = 1024 chunks of 8
#pragma unroll
  for (int it = 0; it < 4; ++it) {
    int idx = tid + (it << 8);          // 0..1023
    int row = idx >> 4, j8 = (idx & 15) << 3;
    *(u16x8*)(Wg + (ch << 13) + (row << 7) + j8) = *(const u16x8*)&WR[row * 136 + j8];
  }
}

// ---------------- sequential chunked delta-rule scan (lean) ----------------
// 128 blocks: h = bx&15, v-slice = (bx>>4)*16. Per chunk:
//   Delta = U - W*S ; O = Q*S + G*Delta ; S += K^T Delta
// All chunk-constant fragments stream global->VGPR, prefetched 1 chunk ahead.
struct Frags { short8 q[4], w[4], g[2], k[4]; u16x4 u; };

DEVI void load_frags(Frags& f, const u16* qh, const u16* Wg, const u16* Gg,
                     const u16* KTg, const u16* UTg, int c, int h,
                     int trow, int fr, int fq, int q4, int w, int vbase) {
  const u16* qb = qh + ((size_t)((c << 6) + trow + fr) << 7) + fq;
#pragma unroll
  for (int ks = 0; ks < 4; ++ks) f.q[ks] = *(const short8*)(qb + (ks << 5));
  size_t ch = (size_t)(c * 16 + h);
  const u16* wb = Wg + (ch << 13) + ((size_t)(trow + fr) << 7) + fq;
#pragma unroll
  for (int ks = 0; ks < 4; ++ks) f.w[ks] = *(const short8*)(wb + (ks << 5));
  const u16* gb = Gg + (ch << 12) + ((size_t)(trow + fr) << 6) + fq;
#pragma unroll
  for (int ks = 0; ks < 2; ++ks) f.g[ks] = *(const short8*)(gb + (ks << 5));
  const u16* kbp = KTg + (ch << 13) + ((size_t)(w << 5) << 6) + fq;
#pragma unroll
  for (int dt = 0; dt < 2; ++dt)
#pragma unroll
    for (int ks = 0; ks < 2; ++ks)
      f.k[(dt << 1) | ks] = *(const short8*)(kbp + ((size_t)((dt << 4) + fr) << 6) + (ks << 5));
  f.u = *(const u16x4*)(UTg + (ch << 13) + ((size_t)(vbase + fr) << 6) + trow + q4);
}

DEVI void chunk_body(int c, Frags& f, u16* ST, u16* DT, float* oh,
                     int trow, int fr, int fq, int q4, int w, int vbase,
                     f32x4& S0, f32x4& S1) {
  // publish S^T (this wave's 32 d-columns)
#pragma unroll
  for (int r = 0; r < 4; ++r) {
    ST[(q4 + r) * 136 + (w << 5) + fr] = f2b(S0[r]);
    ST[(q4 + r) * 136 + (w << 5) + 16 + fr] = f2b(S1[r]);
  }
  barrier_lds();
  short8 sf[4];
#pragma unroll
  for (int ks = 0; ks < 4; ++ks) sf[ks] = *(const short8*)&ST[fr * 136 + (ks << 5) + fq];
  f32x4 racc = {0.f,0.f,0.f,0.f}, oacc = {0.f,0.f,0.f,0.f};
#pragma unroll
  for (int ks = 0; ks < 4; ++ks) {
    racc = mfma_bf16(f.w[ks], sf[ks], racc);
    oacc = mfma_bf16(f.q[ks], sf[ks], oacc);
  }
  // Delta = U - W*S, publish Delta^T
#pragma unroll
  for (int r = 0; r < 4; ++r)
    DT[fr * 72 + trow + q4 + r] = f2b(b2f(f.u[r]) - racc[r]);
  barrier_lds();
  short8 df[2];
#pragma unroll
  for (int ks = 0; ks < 2; ++ks) df[ks] = *(const short8*)&DT[fr * 72 + (ks << 5) + fq];
#pragma unroll
  for (int ks = 0; ks < 2; ++ks) {
    oacc = mfma_bf16(f.g[ks], df[ks], oacc);
    S0 = mfma_bf16(df[ks], f.k[ks], S0);
    S1 = mfma_bf16(df[ks], f.k[2 | ks], S1);
  }
#pragma unroll
  for (int r = 0; r < 4; ++r)
    oh[(size_t)((c << 6) + trow + q4 + r) * 128 + vbase + fr] = oacc[r];
}

__global__ __launch_bounds__(256, 1)
void k_delta(const u16* __restrict__ qn, const u16* __restrict__ Wg,
             const u16* __restrict__ Gg, const u16* __restrict__ KTg,
             const u16* __restrict__ UTg, float* __restrict__ o) {
  __shared__ __align__(16) u16 ST[16 * 136];
  __shared__ __align__(16) u16 DT[16 * 72];
  int bx = blockIdx.x;
  int h = bx & 15, vbase = (bx >> 4) << 4;
  int tid = threadIdx.x, w = tid >> 6, lane = tid & 63;
  int fr = lane & 15, fq = (lane >> 4) << 3, q4 = (lane >> 4) << 2;
  int trow = w << 4;
  const u16* qh = qn + ((size_t)h << 18);
  float* oh = o + ((size_t)h << 18);
  f32x4 S0 = {0.f,0.f,0.f,0.f}, S1 = {0.f,0.f,0.f,0.f};
  Frags fa, fb;
  load_frags(fa, qh, Wg, Gg, KTg, UTg, 0, h, trow, fr, fq, q4, w, vbase);
  for (int c = 0; c < 32; c += 2) {
    int c1 = c + 1, c2 = (c + 2 < 32) ? c + 2 : 31;
    load_frags(fb, qh, Wg, Gg, KTg, UTg, c1, h, trow, fr, fq, q4, w, vbase);
    chunk_body(c, fa, ST, DT, oh, trow, fr, fq, q4, w, vbase, S0, S1);
    load_frags(fa, qh, Wg, Gg, KTg, UTg, c2, h, trow, fr, fq, q4, w, vbase);
    chunk_body(c1, fb, ST, DT, oh, trow, fr, fq, q4, w, vbase, S0, S1);
  }
}

// ---------------- per-head RMSNorm on o, emit bf16 [T][H*128] ----------------
__global__ void k_onorm(const float* __restrict__ o, const float* __restrict__ onw,
                        u16* __restrict__ onb) {
  int t = blockIdx.x, h = blockIdx.y, d = threadIdx.x;
  float x = o[((size_t)h << 18) + ((size_t)t << 7) + d];
  float ss = x * x;
#pragma unroll
  for (int off = 32; off; off >>= 1) ss += __shfl_down(ss, off, 64);
  __shared__ float red[2];
  int lane = d & 63, wv = d >> 6;
  if (lane == 0) red[wv] = ss;
  __syncthreads();
  float tot = red[0] + red[1];
  float y = x * rsqrtf(tot * (1.f / 128.f) + 1e-6f) * onw[d];
  onb[((size_t)t << 11) + (h << 7) + d] = f2b(y);
}

extern "C" void kernel_launch(void* const* d_in, const int* in_sizes, int n_in,
                              void* d_out, int out_size, void* d_ws, size_t ws_size,
                              hipStream_t stream) {
  (void)in_sizes; (void)n_in; (void)out_size; (void)ws_size;
  const float* hs  = (const float*)d_in[0];
  const float* Wq  = (const float*)d_in[1];
  const float* Wk  = (const float*)d_in[2];
  const float* Wv  = (const float*)d_in[3];
  const float* Wb  = (const float*)d_in[4];
  const float* cwq = (const float*)d_in[5];
  const float* cwk = (const float*)d_in[6];
  const float* cwv = (const float*)d_in[7];
  const float* onw = (const float*)d_in[8];
  const float* Wo  = (const float*)d_in[9];
  float* out = (float*)d_out;
  char* ws = (char*)d_ws;
  const size_t MB = 1ull << 20;
  u16*  Xb   = (u16*)(ws);              //  8 MB  hs bf16 [2048][2048]
  u16*  WT   = (u16*)(ws + 8  * MB);    // 24 MB  [Wq|Wk|Wv]^T bf16 [6144][2048]
  u16*  WoT  = (u16*)(ws + 32 * MB);    //  8 MB  Wo^T bf16
  u16*  QKV  = (u16*)(ws + 40 * MB);    // 24 MB  qkv pre-activations (dead after k_conv)
  u16*  Wg   = (u16*)(ws + 40 * MB);    //  8 MB  overlays dead QKV
  u16*  KTg  = (u16*)(ws + 48 * MB);    //  8 MB
  u16*  UTg  = (u16*)(ws + 56 * MB);    //  8 MB
  u16*  qn_  = (u16*)(ws + 64 * MB);    //  8 MB  [16][2048][128]
  u16*  kn_  = (u16*)(ws + 72 * MB);    //  8 MB
  u16*  vn_  = (u16*)(ws + 80 * MB);    //  8 MB
  float* beta= (float*)(ws + 88 * MB);  //  128KB [2048][16]
  u16*  WbT  = (u16*)(ws + 88 * MB + 512 * 1024);  // 64KB [16][2048]
  u16*  Gm   = (u16*)(ws + 89 * MB);    //  4 MB  [32*16][64][64]
  float* o_  = (float*)(ws + 93 * MB);  // 16 MB  [16][2048][128]
  u16*  onb  = (u16*)(ws + 109 * MB);   //  8 MB  [2048][2048]

  dim3 tb(32, 8);
  k_cvt<<<4096, 256, 0, stream>>>(hs, Xb, 2048 * 2048 / 4);
  k_wbT<<<128, 256, 0, stream>>>(Wb, WbT);
  k_transpose<<<dim3(64, 64), tb, 0, stream>>>(Wq, WT,                   2048, 2048);
  k_transpose<<<dim3(64, 64), tb, 0, stream>>>(Wk, WT + 2048 * 2048,     2048, 2048);
  k_transpose<<<dim3(64, 64), tb, 0, stream>>>(Wv, WT + 2 * 2048 * 2048, 2048, 2048);
  k_transpose<<<dim3(64, 64), tb, 0, stream>>>(Wo, WoT,                  2048, 2048);
  k_gemm_bt<<<dim3(48, 16), 256, 0, stream>>>(Xb, WT, nullptr, QKV, 2048, 6144, 2048, 1);
  k_beta<<<128, 256, 0, stream>>>(Xb, WbT, beta);
  k_conv<<<dim3(2048, 48), 128, 0, stream>>>(QKV, cwq, cwk, cwv, qn_, kn_, vn_);
  k_prep<<<dim3(16, 32), 256, 0, stream>>>(qn_, kn_, vn_, beta, Gm, Wg, KTg, UTg);
  k_delta<<<128, 256, 0, stream>>>(qn_, Wg, Gm, KTg, UTg, o_);
  k_onorm<<<dim3(2048, 16), 128, 0, stream>>>(o_, onw, onb);
  k_gemm_bt<<<dim3(16, 16), 256, 0, stream>>>(onb, WoT, out, nullptr, 2048, 2048, 2048, 0);
}

// Round 5
// 388.844 us; speedup vs baseline: 1.5717x; 1.0276x over previous
//
#include <hip/hip_runtime.h>

typedef unsigned short u16;
typedef __attribute__((ext_vector_type(4))) unsigned short u16x4;
typedef __attribute__((ext_vector_type(8))) unsigned short u16x8;
typedef __attribute__((ext_vector_type(8))) short short8;
typedef __attribute__((ext_vector_type(4))) float f32x4;

#define DEVI __device__ __forceinline__

DEVI u16 f2b(float f) {
  union { float f; unsigned u; } x; x.f = f;
  unsigned r = (x.u + 0x7fffu + ((x.u >> 16) & 1u)) >> 16;
  return (u16)r;
}
DEVI float b2f(u16 h) {
  union { unsigned u; float f; } x; x.u = ((unsigned)h) << 16;
  return x.f;
}
DEVI f32x4 mfma_bf16(short8 a, short8 b, f32x4 c) {
  return __builtin_amdgcn_mfma_f32_16x16x32_bf16(a, b, c, 0, 0, 0);
}
DEVI void gl2lds16(const u16* g, u16* l) {
  __builtin_amdgcn_global_load_lds((__attribute__((address_space(1))) void*)g,
                                   (__attribute__((address_space(3))) void*)l,
                                   16, 0, 0);
}
// barrier that drains only LDS (lgkmcnt), NOT vmcnt -> global prefetch stays in flight
DEVI void barrier_lds() {
  asm volatile("s_waitcnt lgkmcnt(0)\n\ts_barrier" ::: "memory");
}

// ---------------- fp32 -> bf16 convert (hidden_states) + WbT build ----------------
__global__ void k_cvt(const float* __restrict__ src, u16* __restrict__ dst, int n4,
                      const float* __restrict__ Wb, u16* __restrict__ WbT) {
  int b = blockIdx.x;
  if (b < 4096) {
    int i = b * 256 + threadIdx.x;
    if (i < n4) {
      float4 v = ((const float4*)src)[i];
      u16x4 r; r.x = f2b(v.x); r.y = f2b(v.y); r.z = f2b(v.z); r.w = f2b(v.w);
      ((u16x4*)dst)[i] = r;
    }
  } else {
    int j = (b - 4096) * 256 + threadIdx.x;   // 0..32767
    int n = j >> 11, k = j & 2047;
    WbT[j] = f2b(Wb[k * 16 + n]);
  }
}

// ---------------- 4x tiled transpose fp32[2048][2048] -> bf16 transposed ----------------
__global__ __launch_bounds__(256)
void k_transpose4(const float* __restrict__ s0, const float* __restrict__ s1,
                  const float* __restrict__ s2, const float* __restrict__ s3,
                  u16* __restrict__ d0, u16* __restrict__ d1,
                  u16* __restrict__ d2, u16* __restrict__ d3) {
  const int RC = 2048;
  const float* src = (blockIdx.z == 0) ? s0 : (blockIdx.z == 1) ? s1 : (blockIdx.z == 2) ? s2 : s3;
  u16* dst = (blockIdx.z == 0) ? d0 : (blockIdx.z == 1) ? d1 : (blockIdx.z == 2) ? d2 : d3;
  __shared__ u16 tile[64 * 66];
  int bx = blockIdx.x << 6, by = blockIdx.y << 6;
  int x = threadIdx.x & 63, g = threadIdx.x >> 6;
#pragma unroll
  for (int i = 0; i < 16; ++i) {
    int r = (i << 2) + g;
    tile[x * 66 + r] = f2b(src[(size_t)(by + r) * RC + bx + x]);  // transposed into LDS
  }
  __syncthreads();
#pragma unroll
  for (int i = 0; i < 16; ++i) {
    int r = (i << 2) + g;
    dst[(size_t)(bx + r) * RC + by + x] = tile[r * 66 + x];       // 128B coalesced rows
  }
}

// ---------------- bf16 MFMA GEMM: C[M][N] = A[M][K] @ BT[N][K]^T ----------------
// LDS chunk XOR-swizzle: staging lane fetches k-chunk (l&3)^((l>>3)&3); fragment read
// applies fq ^ ((fr>>1)&3)<<3. Spreads 64B-stride reads over all 8 bank groups (2-way).
__global__ __launch_bounds__(256, 2)
void k_gemm_bt(const u16* __restrict__ A, const u16* __restrict__ BT,
               float* __restrict__ Cf, u16* __restrict__ Cb,
               int M, int N, int K, int outbf) {
  __shared__ __align__(16) u16 As[4096];
  __shared__ __align__(16) u16 Bs[4096];
  const int tid = threadIdx.x, wave = tid >> 6, lane = tid & 63;
  const long bm = (long)blockIdx.y << 7, bn = (long)blockIdx.x << 7;
  const int r0 = (wave << 4) + (lane >> 2);
  const int kof = (((lane & 3) ^ ((lane >> 3) & 3)) << 3);   // swizzled chunk fetch
  const u16* gA = A + (bm + r0) * (long)K + kof;
  const u16* gB = BT + (bn + r0) * (long)K + kof;
  u16* lA = As + (wave << 9);
  u16* lB = Bs + (wave << 9);
  const long stepR = (long)64 * K;
  const int wr = (wave >> 1) << 6, wc = (wave & 1) << 6;
  const int fr = lane & 15, fq = (lane >> 4) << 3;
  const int sw = ((fr >> 1) & 3) << 3;                        // read-side inverse swizzle
  const int fqs = fq ^ sw;
  f32x4 acc[4][4];
#pragma unroll
  for (int i = 0; i < 4; ++i)
#pragma unroll
    for (int j = 0; j < 4; ++j) acc[i][j] = (f32x4){0.f, 0.f, 0.f, 0.f};
  for (int k0 = 0; k0 < K; k0 += 32) {
    gl2lds16(gA + k0, lA);
    gl2lds16(gA + stepR + k0, lA + 2048);
    gl2lds16(gB + k0, lB);
    gl2lds16(gB + stepR + k0, lB + 2048);
    __syncthreads();
    short8 af[4], bfr[4];
#pragma unroll
    for (int t = 0; t < 4; ++t)
      af[t] = *(const short8*)&As[(wr + (t << 4) + fr) * 32 + fqs];
#pragma unroll
    for (int t = 0; t < 4; ++t)
      bfr[t] = *(const short8*)&Bs[(wc + (t << 4) + fr) * 32 + fqs];
#pragma unroll
    for (int i = 0; i < 4; ++i)
#pragma unroll
      for (int j = 0; j < 4; ++j)
        acc[i][j] = mfma_bf16(af[i], bfr[j], acc[i][j]);
    __syncthreads();
  }
  const int er = (lane >> 4) << 2, ec = lane & 15;
#pragma unroll
  for (int i = 0; i < 4; ++i)
#pragma unroll
    for (int j = 0; j < 4; ++j)
#pragma unroll
      for (int r = 0; r < 4; ++r) {
        long row = bm + wr + (i << 4) + er + r;
        long col = bn + wc + (j << 4) + ec;
        if (outbf) Cb[row * N + col] = f2b(acc[i][j][r]);
        else       Cf[row * N + col] = acc[i][j][r];
      }
}

// ---------------- beta = sigmoid(hs @ Wb) via MFMA ----------------
__global__ __launch_bounds__(256, 4)
void k_beta(const u16* __restrict__ Xb, const u16* __restrict__ WbT,
            float* __restrict__ beta) {
  __shared__ float part[4][256];
  int tid = threadIdx.x, w = tid >> 6, lane = tid & 63;
  int t0 = blockIdx.x << 4;
  int fr = lane & 15, fq = (lane >> 4) << 3;
  const u16* ap = Xb + (size_t)(t0 + fr) * 2048 + (w << 9) + fq;
  const u16* bp = WbT + (size_t)fr * 2048 + (w << 9) + fq;
  f32x4 acc = {0.f, 0.f, 0.f, 0.f};
#pragma unroll
  for (int ks = 0; ks < 16; ++ks)
    acc = mfma_bf16(*(const short8*)(ap + (ks << 5)), *(const short8*)(bp + (ks << 5)), acc);
  int er = (lane >> 4) << 2;
#pragma unroll
  for (int r = 0; r < 4; ++r) part[w][(er + r) * 16 + fr] = acc[r];
  __syncthreads();
  float s = part[0][tid] + part[1][tid] + part[2][tid] + part[3][tid];
  beta[(t0 << 4) + tid] = 1.f / (1.f + __expf(-s));
}

// ---------------- causal conv(K=4) + SiLU + (l2norm for q,k) ----------------
__global__ void k_conv(const u16* __restrict__ qkv,
                       const float* __restrict__ cwq, const float* __restrict__ cwk,
                       const float* __restrict__ cwv,
                       u16* __restrict__ qn, u16* __restrict__ kn, u16* __restrict__ vn) {
  int t = blockIdx.x, s = blockIdx.y;
  int kind = s >> 4, h = s & 15, d = threadIdx.x;
  int col = kind * 2048 + (h << 7) + d;
  const float* cw = (kind == 0) ? cwq : ((kind == 1) ? cwk : cwv);
  float4 w = *(const float4*)(cw + (size_t)((h << 7) + d) * 4);
  float x[4];
#pragma unroll
  for (int j = 0; j < 4; ++j) {
    int tt = t - 3 + j;
    x[j] = (tt >= 0) ? b2f(qkv[(size_t)tt * 6144 + col]) : 0.f;
  }
  float y = x[0] * w.x + x[1] * w.y + x[2] * w.z + x[3] * w.w;
  y = y / (1.f + __expf(-y));  // SiLU
  float sc = 1.f;
  __shared__ float red[2];
  if (kind < 2) {
    float ss = y * y;
#pragma unroll
    for (int off = 32; off; off >>= 1) ss += __shfl_down(ss, off, 64);
    int lane = threadIdx.x & 63, wv = threadIdx.x >> 6;
    if (lane == 0) red[wv] = ss;
    __syncthreads();
    float tot = red[0] + red[1];
    sc = rsqrtf(tot + 1e-6f);
    if (kind == 0) sc *= 0.08838834764831843f;  // 128^-0.5
  }
  u16* dst = (kind == 0) ? qn : ((kind == 1) ? kn : vn);
  dst[((size_t)h << 18) + ((size_t)t << 7) + d] = f2b(y * sc);
}

// ---------------- per-(chunk,head) parallel prep (v3) ----------------
__global__ __launch_bounds__(256, 2)
void k_prep(const u16* __restrict__ qn, const u16* __restrict__ kn, const u16* __restrict__ vn,
            const float* __restrict__ beta,
            u16* __restrict__ Gg, u16* __restrict__ Wg,
            u16* __restrict__ KTg, u16* __restrict__ UTg) {
  __shared__ __align__(16) char sm[70912];
  u16*  Kc  = (u16*)sm;                 // 64*136*2 = 17408
  u16*  Qc  = (u16*)(sm + 17408);       // 17408 ; overlay: WR
  u16*  Vc  = (u16*)(sm + 34816);       // 17408
  u16*  KTl = (u16*)(sm + 52224);       // 128*72*2 = 18432 ; overlay: AL (64*64*4)
  float* AL = (float*)(sm + 52224);
  float* Bl = (float*)(sm + 70656);     // 256
  u16*  WR  = Qc;
  int h = blockIdx.x, c = blockIdx.y;
  int tid = threadIdx.x, wave = tid >> 6, lane = tid & 63;
  size_t ch = (size_t)(c * 16 + h);
  const u16* kb = kn + ((size_t)h << 18) + ((size_t)c << 13);
  const u16* qb = qn + ((size_t)h << 18) + ((size_t)c << 13);
  const u16* vb = vn + ((size_t)h << 18) + ((size_t)c << 13);
#pragma unroll
  for (int s = 0; s < 4; ++s) {
    int e = (tid + (s << 8)) << 3;
    int t = e >> 7, d = e & 127;
    *(u16x8*)&Kc[t * 136 + d] = *(const u16x8*)(kb + e);
    *(u16x8*)&Qc[t * 136 + d] = *(const u16x8*)(qb + e);
    *(u16x8*)&Vc[t * 136 + d] = *(const u16x8*)(vb + e);
  }
  if (tid < 64) Bl[tid] = beta[((c << 6) + tid) * 16 + h];
  __syncthreads();
  int fr = lane & 15, fq = (lane >> 4) << 3, q4 = (lane >> 4) << 2;
  int arow = (wave << 4) + fr;
  f32x4 kk[4], qk[4];
#pragma unroll
  for (int ct = 0; ct < 4; ++ct) { kk[ct] = (f32x4){0.f,0.f,0.f,0.f}; qk[ct] = (f32x4){0.f,0.f,0.f,0.f}; }
#pragma unroll
  for (int ks = 0; ks < 4; ++ks) {
    short8 aK = *(const short8*)&Kc[arow * 136 + (ks << 5) + fq];
    short8 aQ = *(const short8*)&Qc[arow * 136 + (ks << 5) + fq];
#pragma unroll
    for (int ct = 0; ct < 4; ++ct) {
      short8 bK = *(const short8*)&Kc[((ct << 4) + fr) * 136 + (ks << 5) + fq];
      kk[ct] = mfma_bf16(aK, bK, kk[ct]);
      qk[ct] = mfma_bf16(aQ, bK, qk[ct]);
    }
  }
#pragma unroll
  for (int ct = 0; ct < 4; ++ct)
#pragma unroll
    for (int r = 0; r < 4; ++r) {
      int i = (wave << 4) + q4 + r, j = (ct << 4) + fr;
      Gg[(ch << 12) + i * 64 + j] = f2b((j <= i) ? qk[ct][r] : 0.f);
    }
  // K^T into KTl
  {
    int d = tid & 127, tg = tid >> 7;
#pragma unroll
    for (int it = 0; it < 4; ++it) {
      int t0 = (tg + (it << 1)) << 3;
      u16x8 pk;
#pragma unroll
      for (int j = 0; j < 8; ++j) pk[j] = Kc[(t0 + j) * 136 + d];
      *(u16x8*)&KTl[d * 72 + t0] = pk;
    }
  }
  __syncthreads();
#pragma unroll
  for (int it = 0; it < 4; ++it) {
    int idx = tid + (it << 8);
    int row = idx >> 3, j8 = (idx & 7) << 3;
    *(u16x8*)(KTg + (ch << 13) + (row << 6) + j8) = *(const u16x8*)&KTl[row * 72 + j8];
  }
  __syncthreads();
  {
    float bi[4];
#pragma unroll
    for (int r = 0; r < 4; ++r) bi[r] = Bl[(wave << 4) + q4 + r];
#pragma unroll
    for (int ct = 0; ct < 4; ++ct)
#pragma unroll
      for (int r = 0; r < 4; ++r) {
        int i = (wave << 4) + q4 + r, j = (ct << 4) + fr;
        AL[i * 64 + j] = (j < i) ? bi[r] * kk[ct][r] : 0.f;
      }
  }
  __syncthreads();
  float X[64];
  {
    const u16* colp = (tid < 128) ? (Kc + tid) : (Vc + (tid - 128));
#pragma unroll
    for (int t = 0; t < 64; ++t) X[t] = Bl[t] * b2f(colp[t * 136]);
#pragma unroll
    for (int r = 1; r < 64; ++r) {
      float s = 0.f;
      const float* Ar = &AL[r * 64];
      int r4 = r & ~3;
#pragma unroll
      for (int l = 0; l < 64; l += 4)
        if (l + 4 <= r) {
          float4 a = *(const float4*)(Ar + l);
          s += a.x * X[l] + a.y * X[l + 1] + a.z * X[l + 2] + a.w * X[l + 3];
        }
#pragma unroll
      for (int l = 0; l < 4; ++l)
        if (r4 + l < r) s += Ar[r4 + l] * X[r4 + l];
      X[r] -= s;
    }
  }
  __syncthreads();   // Qc dead -> WR overlay
  if (tid < 128) {
#pragma unroll
    for (int t = 0; t < 64; ++t) WR[t * 136 + tid] = f2b(X[t]);
  } else {
    int v = tid - 128;
    u16* dstr = UTg + (ch << 13) + (v << 6);
#pragma unroll
    for (int j = 0; j < 8; ++j) {
      u16x8 p;
#pragma unroll
      for (int e = 0; e < 8; ++e) p[e] = f2b(X[(j << 3) + e]);
      *(u16x8*)(dstr + (j << 3)) = p;
    }
  }
  __syncthreads();
#pragma unroll
  for (int it = 0; it < 4; ++it) {
    int idx = tid + (it << 8);
    int row = idx >> 4, j8 = (idx & 15) << 3;
    *(u16x8*)(Wg + (ch << 13) + (row << 7) + j8) = *(const u16x8*)&WR[row * 136 + j8];
  }
}

// ---------------- sequential chunked delta-rule scan (lean) ----------------
struct Frags { short8 q[4], w[4], g[2], k[4]; u16x4 u; };

DEVI void load_frags(Frags& f, const u16* qh, const u16* Wg, const u16* Gg,
                     const u16* KTg, const u16* UTg, int c, int h,
                     int trow, int fr, int fq, int q4, int w, int vbase) {
  const u16* qb = qh + ((size_t)((c << 6) + trow + fr) << 7) + fq;
#pragma unroll
  for (int ks = 0; ks < 4; ++ks) f.q[ks] = *(const short8*)(qb + (ks << 5));
  size_t ch = (size_t)(c * 16 + h);
  const u16* wb = Wg + (ch << 13) + ((size_t)(trow + fr) << 7) + fq;
#pragma unroll
  for (int ks = 0; ks < 4; ++ks) f.w[ks] = *(const short8*)(wb + (ks << 5));
  const u16* gb = Gg + (ch << 12) + ((size_t)(trow + fr) << 6) + fq;
#pragma unroll
  for (int ks = 0; ks < 2; ++ks) f.g[ks] = *(const short8*)(gb + (ks << 5));
  const u16* kbp = KTg + (ch << 13) + ((size_t)(w << 5) << 6) + fq;
#pragma unroll
  for (int dt = 0; dt < 2; ++dt)
#pragma unroll
    for (int ks = 0; ks < 2; ++ks)
      f.k[(dt << 1) | ks] = *(const short8*)(kbp + ((size_t)((dt << 4) + fr) << 6) + (ks << 5));
  f.u = *(const u16x4*)(UTg + (ch << 13) + ((size_t)(vbase + fr) << 6) + trow + q4);
}

DEVI void chunk_body(int c, Frags& f, u16* ST, u16* DT, float* oh,
                     int trow, int fr, int fq, int q4, int w, int vbase,
                     f32x4& S0, f32x4& S1) {
#pragma unroll
  for (int r = 0; r < 4; ++r) {
    ST[(q4 + r) * 136 + (w << 5) + fr] = f2b(S0[r]);
    ST[(q4 + r) * 136 + (w << 5) + 16 + fr] = f2b(S1[r]);
  }
  barrier_lds();
  short8 sf[4];
#pragma unroll
  for (int ks = 0; ks < 4; ++ks) sf[ks] = *(const short8*)&ST[fr * 136 + (ks << 5) + fq];
  f32x4 racc = {0.f,0.f,0.f,0.f}, oacc = {0.f,0.f,0.f,0.f};
#pragma unroll
  for (int ks = 0; ks < 4; ++ks) {
    racc = mfma_bf16(f.w[ks], sf[ks], racc);
    oacc = mfma_bf16(f.q[ks], sf[ks], oacc);
  }
#pragma unroll
  for (int r = 0; r < 4; ++r)
    DT[fr * 72 + trow + q4 + r] = f2b(b2f(f.u[r]) - racc[r]);
  barrier_lds();
  short8 df[2];
#pragma unroll
  for (int ks = 0; ks < 2; ++ks) df[ks] = *(const short8*)&DT[fr * 72 + (ks << 5) + fq];
#pragma unroll
  for (int ks = 0; ks < 2; ++ks) {
    oacc = mfma_bf16(f.g[ks], df[ks], oacc);
    S0 = mfma_bf16(df[ks], f.k[ks], S0);
    S1 = mfma_bf16(df[ks], f.k[2 | ks], S1);
  }
#pragma unroll
  for (int r = 0; r < 4; ++r)
    oh[(size_t)((c << 6) + trow + q4 + r) * 128 + vbase + fr] = oacc[r];
}

__global__ __launch_bounds__(256, 1)
void k_delta(const u16* __restrict__ qn, const u16* __restrict__ Wg,
             const u16* __restrict__ Gg, const u16* __restrict__ KTg,
             const u16* __restrict__ UTg, float* __restrict__ o) {
  __shared__ __align__(16) u16 ST[16 * 136];
  __shared__ __align__(16) u16 DT[16 * 72];
  int bx = blockIdx.x;
  int h = bx & 15, vbase = (bx >> 4) << 4;
  int tid = threadIdx.x, w = tid >> 6, lane = tid & 63;
  int fr = lane & 15, fq = (lane >> 4) << 3, q4 = (lane >> 4) << 2;
  int trow = w << 4;
  const u16* qh = qn + ((size_t)h << 18);
  float* oh = o + ((size_t)h << 18);
  f32x4 S0 = {0.f,0.f,0.f,0.f}, S1 = {0.f,0.f,0.f,0.f};
  Frags fa, fb;
  load_frags(fa, qh, Wg, Gg, KTg, UTg, 0, h, trow, fr, fq, q4, w, vbase);
  for (int c = 0; c < 32; c += 2) {
    int c1 = c + 1, c2 = (c + 2 < 32) ? c + 2 : 31;
    load_frags(fb, qh, Wg, Gg, KTg, UTg, c1, h, trow, fr, fq, q4, w, vbase);
    chunk_body(c, fa, ST, DT, oh, trow, fr, fq, q4, w, vbase, S0, S1);
    load_frags(fa, qh, Wg, Gg, KTg, UTg, c2, h, trow, fr, fq, q4, w, vbase);
    chunk_body(c1, fb, ST, DT, oh, trow, fr, fq, q4, w, vbase, S0, S1);
  }
}

// ---------------- per-head RMSNorm on o, emit bf16 [T][H*128] ----------------
__global__ void k_onorm(const float* __restrict__ o, const float* __restrict__ onw,
                        u16* __restrict__ onb) {
  int t = blockIdx.x, h = blockIdx.y, d = threadIdx.x;
  float x = o[((size_t)h << 18) + ((size_t)t << 7) + d];
  float ss = x * x;
#pragma unroll
  for (int off = 32; off; off >>= 1) ss += __shfl_down(ss, off, 64);
  __shared__ float red[2];
  int lane = d & 63, wv = d >> 6;
  if (lane == 0) red[wv] = ss;
  __syncthreads();
  float tot = red[0] + red[1];
  float y = x * rsqrtf(tot * (1.f / 128.f) + 1e-6f) * onw[d];
  onb[((size_t)t << 11) + (h << 7) + d] = f2b(y);
}

extern "C" void kernel_launch(void* const* d_in, const int* in_sizes, int n_in,
                              void* d_out, int out_size, void* d_ws, size_t ws_size,
                              hipStream_t stream) {
  (void)in_sizes; (void)n_in; (void)out_size; (void)ws_size;
  const float* hs  = (const float*)d_in[0];
  const float* Wq  = (const float*)d_in[1];
  const float* Wk  = (const float*)d_in[2];
  const float* Wv  = (const float*)d_in[3];
  const float* Wb  = (const float*)d_in[4];
  const float* cwq = (const float*)d_in[5];
  const float* cwk = (const float*)d_in[6];
  const float* cwv = (const float*)d_in[7];
  const float* onw = (const float*)d_in[8];
  const float* Wo  = (const float*)d_in[9];
  float* out = (float*)d_out;
  char* ws = (char*)d_ws;
  const size_t MB = 1ull << 20;
  u16*  Xb   = (u16*)(ws);              //  8 MB  hs bf16 [2048][2048]
  u16*  WT   = (u16*)(ws + 8  * MB);    // 24 MB  [Wq|Wk|Wv]^T bf16 [6144][2048]
  u16*  WoT  = (u16*)(ws + 32 * MB);    //  8 MB  Wo^T bf16
  u16*  QKV  = (u16*)(ws + 40 * MB);    // 24 MB  qkv pre-activations (dead after k_conv)
  u16*  Wg   = (u16*)(ws + 40 * MB);    //  8 MB  overlays dead QKV
  u16*  KTg  = (u16*)(ws + 48 * MB);    //  8 MB
  u16*  UTg  = (u16*)(ws + 56 * MB);    //  8 MB
  u16*  qn_  = (u16*)(ws + 64 * MB);    //  8 MB  [16][2048][128]
  u16*  kn_  = (u16*)(ws + 72 * MB);    //  8 MB
  u16*  vn_  = (u16*)(ws + 80 * MB);    //  8 MB
  float* beta= (float*)(ws + 88 * MB);  //  128KB [2048][16]
  u16*  WbT  = (u16*)(ws + 88 * MB + 512 * 1024);  // 64KB [16][2048]
  u16*  Gm   = (u16*)(ws + 89 * MB);    //  4 MB  [32*16][64][64]
  float* o_  = (float*)(ws + 93 * MB);  // 16 MB  [16][2048][128]
  u16*  onb  = (u16*)(ws + 109 * MB);   //  8 MB  [2048][2048]

  k_cvt<<<4224, 256, 0, stream>>>(hs, Xb, 2048 * 2048 / 4, Wb, WbT);
  k_transpose4<<<dim3(32, 32, 4), 256, 0, stream>>>(
      Wq, Wk, Wv, Wo, WT, WT + 2048 * 2048, WT + 2 * 2048 * 2048, WoT);
  k_gemm_bt<<<dim3(48, 16), 256, 0, stream>>>(Xb, WT, nullptr, QKV, 2048, 6144, 2048, 1);
  k_beta<<<128, 256, 0, stream>>>(Xb, WbT, beta);
  k_conv<<<dim3(2048, 48), 128, 0, stream>>>(QKV, cwq, cwk, cwv, qn_, kn_, vn_);
  k_prep<<<dim3(16, 32), 256, 0, stream>>>(qn_, kn_, vn_, beta, Gm, Wg, KTg, UTg);
  k_delta<<<128, 256, 0, stream>>>(qn_, Wg, Gm, KTg, UTg, o_);
  k_onorm<<<dim3(2048, 16), 128, 0, stream>>>(o_, onw, onb);
  k_gemm_bt<<<dim3(16, 16), 256, 0, stream>>>(onb, WoT, out, nullptr, 2048, 2048, 2048, 0);
}

// Round 6
// 374.534 us; speedup vs baseline: 1.6317x; 1.0382x over previous
//
#include <hip/hip_runtime.h>

typedef unsigned short u16;
typedef __attribute__((ext_vector_type(4))) unsigned short u16x4;
typedef __attribute__((ext_vector_type(8))) unsigned short u16x8;
typedef __attribute__((ext_vector_type(8))) short short8;
typedef __attribute__((ext_vector_type(4))) float f32x4;

#define DEVI __device__ __forceinline__

DEVI u16 f2b(float f) {
  union { float f; unsigned u; } x; x.f = f;
  unsigned r = (x.u + 0x7fffu + ((x.u >> 16) & 1u)) >> 16;
  return (u16)r;
}
DEVI float b2f(u16 h) {
  union { unsigned u; float f; } x; x.u = ((unsigned)h) << 16;
  return x.f;
}
DEVI f32x4 mfma_bf16(short8 a, short8 b, f32x4 c) {
  return __builtin_amdgcn_mfma_f32_16x16x32_bf16(a, b, c, 0, 0, 0);
}
DEVI void gl2lds16(const u16* g, u16* l) {
  __builtin_amdgcn_global_load_lds((__attribute__((address_space(1))) void*)g,
                                   (__attribute__((address_space(3))) void*)l,
                                   16, 0, 0);
}
// barrier that drains only LDS (lgkmcnt), NOT vmcnt -> global prefetch stays in flight
DEVI void barrier_lds() {
  asm volatile("s_waitcnt lgkmcnt(0)\n\ts_barrier" ::: "memory");
}

// ---------------- fp32 -> bf16 convert (hidden_states) + WbT build ----------------
__global__ void k_cvt(const float* __restrict__ src, u16* __restrict__ dst, int n4,
                      const float* __restrict__ Wb, u16* __restrict__ WbT) {
  int b = blockIdx.x;
  if (b < 4096) {
    int i = b * 256 + threadIdx.x;
    if (i < n4) {
      float4 v = ((const float4*)src)[i];
      u16x4 r; r.x = f2b(v.x); r.y = f2b(v.y); r.z = f2b(v.z); r.w = f2b(v.w);
      ((u16x4*)dst)[i] = r;
    }
  } else {
    int j = (b - 4096) * 256 + threadIdx.x;   // 0..32767
    int n = j >> 11, k = j & 2047;
    WbT[j] = f2b(Wb[k * 16 + n]);
  }
}

// ---------------- 4x tiled transpose fp32[2048][2048] -> bf16 transposed ----------------
__global__ __launch_bounds__(256)
void k_transpose4(const float* __restrict__ s0, const float* __restrict__ s1,
                  const float* __restrict__ s2, const float* __restrict__ s3,
                  u16* __restrict__ d0, u16* __restrict__ d1,
                  u16* __restrict__ d2, u16* __restrict__ d3) {
  const int RC = 2048;
  const float* src = (blockIdx.z == 0) ? s0 : (blockIdx.z == 1) ? s1 : (blockIdx.z == 2) ? s2 : s3;
  u16* dst = (blockIdx.z == 0) ? d0 : (blockIdx.z == 1) ? d1 : (blockIdx.z == 2) ? d2 : d3;
  __shared__ u16 tile[64 * 66];
  int bx = blockIdx.x << 6, by = blockIdx.y << 6;
  int x = threadIdx.x & 63, g = threadIdx.x >> 6;
#pragma unroll
  for (int i = 0; i < 16; ++i) {
    int r = (i << 2) + g;
    tile[x * 66 + r] = f2b(src[(size_t)(by + r) * RC + bx + x]);  // transposed into LDS
  }
  __syncthreads();
#pragma unroll
  for (int i = 0; i < 16; ++i) {
    int r = (i << 2) + g;
    dst[(size_t)(bx + r) * RC + by + x] = tile[r * 66 + x];       // 128B coalesced rows
  }
}

// ---------------- bf16 MFMA GEMM 128x128: C[M][N] = A[M][K] @ BT[N][K]^T ----------------
// XOR chunk swizzle on staging + fragment reads (conflict-free, verified r5: conflicts=0).
// launch_bounds(256,4): 4 blocks/CU so other blocks' MFMA covers this block's barrier drain.
__global__ __launch_bounds__(256, 4)
void k_gemm_bt(const u16* __restrict__ A, const u16* __restrict__ BT,
               float* __restrict__ Cf, u16* __restrict__ Cb,
               int M, int N, int K, int outbf) {
  __shared__ __align__(16) u16 As[4096];
  __shared__ __align__(16) u16 Bs[4096];
  const int tid = threadIdx.x, wave = tid >> 6, lane = tid & 63;
  const long bm = (long)blockIdx.y << 7, bn = (long)blockIdx.x << 7;
  const int r0 = (wave << 4) + (lane >> 2);
  const int kof = (((lane & 3) ^ ((lane >> 3) & 3)) << 3);   // swizzled chunk fetch
  const u16* gA = A + (bm + r0) * (long)K + kof;
  const u16* gB = BT + (bn + r0) * (long)K + kof;
  u16* lA = As + (wave << 9);
  u16* lB = Bs + (wave << 9);
  const long stepR = (long)64 * K;
  const int wr = (wave >> 1) << 6, wc = (wave & 1) << 6;
  const int fr = lane & 15, fq = (lane >> 4) << 3;
  const int fqs = fq ^ (((fr >> 1) & 3) << 3);               // read-side inverse swizzle
  f32x4 acc[4][4];
#pragma unroll
  for (int i = 0; i < 4; ++i)
#pragma unroll
    for (int j = 0; j < 4; ++j) acc[i][j] = (f32x4){0.f, 0.f, 0.f, 0.f};
  for (int k0 = 0; k0 < K; k0 += 32) {
    gl2lds16(gA + k0, lA);
    gl2lds16(gA + stepR + k0, lA + 2048);
    gl2lds16(gB + k0, lB);
    gl2lds16(gB + stepR + k0, lB + 2048);
    __syncthreads();
    short8 af[4], bfr[4];
#pragma unroll
    for (int t = 0; t < 4; ++t)
      af[t] = *(const short8*)&As[(wr + (t << 4) + fr) * 32 + fqs];
#pragma unroll
    for (int t = 0; t < 4; ++t)
      bfr[t] = *(const short8*)&Bs[(wc + (t << 4) + fr) * 32 + fqs];
#pragma unroll
    for (int i = 0; i < 4; ++i)
#pragma unroll
      for (int j = 0; j < 4; ++j)
        acc[i][j] = mfma_bf16(af[i], bfr[j], acc[i][j]);
    __syncthreads();
  }
  const int er = (lane >> 4) << 2, ec = lane & 15;
#pragma unroll
  for (int i = 0; i < 4; ++i)
#pragma unroll
    for (int j = 0; j < 4; ++j)
#pragma unroll
      for (int r = 0; r < 4; ++r) {
        long row = bm + wr + (i << 4) + er + r;
        long col = bn + wc + (j << 4) + ec;
        if (outbf) Cb[row * N + col] = f2b(acc[i][j][r]);
        else       Cf[row * N + col] = acc[i][j][r];
      }
}

// ---------------- bf16 MFMA GEMM 64x128 tile (2x parallelism for small grids) ----------------
__global__ __launch_bounds__(256, 4)
void k_gemm_bt64(const u16* __restrict__ A, const u16* __restrict__ BT,
                 float* __restrict__ Cf, int M, int N, int K) {
  __shared__ __align__(16) u16 As[2048];
  __shared__ __align__(16) u16 Bs[4096];
  const int tid = threadIdx.x, wave = tid >> 6, lane = tid & 63;
  const long bm = (long)blockIdx.y << 6, bn = (long)blockIdx.x << 7;
  const int r0 = (wave << 4) + (lane >> 2);
  const int kof = (((lane & 3) ^ ((lane >> 3) & 3)) << 3);
  const u16* gA = A + (bm + r0) * (long)K + kof;
  const u16* gB = BT + (bn + r0) * (long)K + kof;
  u16* lA = As + (wave << 9);
  u16* lB = Bs + (wave << 9);
  const long stepR = (long)64 * K;
  const int wr = (wave >> 1) << 5, wc = (wave & 1) << 6;
  const int fr = lane & 15, fq = (lane >> 4) << 3;
  const int fqs = fq ^ (((fr >> 1) & 3) << 3);
  f32x4 acc[2][4];
#pragma unroll
  for (int i = 0; i < 2; ++i)
#pragma unroll
    for (int j = 0; j < 4; ++j) acc[i][j] = (f32x4){0.f, 0.f, 0.f, 0.f};
  for (int k0 = 0; k0 < K; k0 += 32) {
    gl2lds16(gA + k0, lA);
    gl2lds16(gB + k0, lB);
    gl2lds16(gB + stepR + k0, lB + 2048);
    __syncthreads();
    short8 af[2], bfr[4];
#pragma unroll
    for (int t = 0; t < 2; ++t)
      af[t] = *(const short8*)&As[(wr + (t << 4) + fr) * 32 + fqs];
#pragma unroll
    for (int t = 0; t < 4; ++t)
      bfr[t] = *(const short8*)&Bs[(wc + (t << 4) + fr) * 32 + fqs];
#pragma unroll
    for (int i = 0; i < 2; ++i)
#pragma unroll
      for (int j = 0; j < 4; ++j)
        acc[i][j] = mfma_bf16(af[i], bfr[j], acc[i][j]);
    __syncthreads();
  }
  const int er = (lane >> 4) << 2, ec = lane & 15;
#pragma unroll
  for (int i = 0; i < 2; ++i)
#pragma unroll
    for (int j = 0; j < 4; ++j)
#pragma unroll
      for (int r = 0; r < 4; ++r) {
        long row = bm + wr + (i << 4) + er + r;
        long col = bn + wc + (j << 4) + ec;
        Cf[row * N + col] = acc[i][j][r];
      }
}

// ---------------- beta = sigmoid(hs @ Wb) via MFMA ----------------
__global__ __launch_bounds__(256, 4)
void k_beta(const u16* __restrict__ Xb, const u16* __restrict__ WbT,
            float* __restrict__ beta) {
  __shared__ float part[4][256];
  int tid = threadIdx.x, w = tid >> 6, lane = tid & 63;
  int t0 = blockIdx.x << 4;
  int fr = lane & 15, fq = (lane >> 4) << 3;
  const u16* ap = Xb + (size_t)(t0 + fr) * 2048 + (w << 9) + fq;
  const u16* bp = WbT + (size_t)fr * 2048 + (w << 9) + fq;
  f32x4 acc = {0.f, 0.f, 0.f, 0.f};
#pragma unroll
  for (int ks = 0; ks < 16; ++ks)
    acc = mfma_bf16(*(const short8*)(ap + (ks << 5)), *(const short8*)(bp + (ks << 5)), acc);
  int er = (lane >> 4) << 2;
#pragma unroll
  for (int r = 0; r < 4; ++r) part[w][(er + r) * 16 + fr] = acc[r];
  __syncthreads();
  float s = part[0][tid] + part[1][tid] + part[2][tid] + part[3][tid];
  beta[(t0 << 4) + tid] = 1.f / (1.f + __expf(-s));
}

// ---------------- causal conv(K=4) + SiLU + (l2norm for q,k) ----------------
__global__ void k_conv(const u16* __restrict__ qkv,
                       const float* __restrict__ cwq, const float* __restrict__ cwk,
                       const float* __restrict__ cwv,
                       u16* __restrict__ qn, u16* __restrict__ kn, u16* __restrict__ vn) {
  int t = blockIdx.x, s = blockIdx.y;
  int kind = s >> 4, h = s & 15, d = threadIdx.x;
  int col = kind * 2048 + (h << 7) + d;
  const float* cw = (kind == 0) ? cwq : ((kind == 1) ? cwk : cwv);
  float4 w = *(const float4*)(cw + (size_t)((h << 7) + d) * 4);
  float x[4];
#pragma unroll
  for (int j = 0; j < 4; ++j) {
    int tt = t - 3 + j;
    x[j] = (tt >= 0) ? b2f(qkv[(size_t)tt * 6144 + col]) : 0.f;
  }
  float y = x[0] * w.x + x[1] * w.y + x[2] * w.z + x[3] * w.w;
  y = y / (1.f + __expf(-y));  // SiLU
  float sc = 1.f;
  __shared__ float red[2];
  if (kind < 2) {
    float ss = y * y;
#pragma unroll
    for (int off = 32; off; off >>= 1) ss += __shfl_down(ss, off, 64);
    int lane = threadIdx.x & 63, wv = threadIdx.x >> 6;
    if (lane == 0) red[wv] = ss;
    __syncthreads();
    float tot = red[0] + red[1];
    sc = rsqrtf(tot + 1e-6f);
    if (kind == 0) sc *= 0.08838834764831843f;  // 128^-0.5
  }
  u16* dst = (kind == 0) ? qn : ((kind == 1) ? kn : vn);
  dst[((size_t)h << 18) + ((size_t)t << 7) + d] = f2b(y * sc);
}

// ---------------- per-(chunk,head) parallel prep (v3) ----------------
__global__ __launch_bounds__(256, 2)
void k_prep(const u16* __restrict__ qn, const u16* __restrict__ kn, const u16* __restrict__ vn,
            const float* __restrict__ beta,
            u16* __restrict__ Gg, u16* __restrict__ Wg,
            u16* __restrict__ KTg, u16* __restrict__ UTg) {
  __shared__ __align__(16) char sm[70912];
  u16*  Kc  = (u16*)sm;                 // 64*136*2 = 17408
  u16*  Qc  = (u16*)(sm + 17408);       // 17408 ; overlay: WR
  u16*  Vc  = (u16*)(sm + 34816);       // 17408
  u16*  KTl = (u16*)(sm + 52224);       // 128*72*2 = 18432 ; overlay: AL (64*64*4)
  float* AL = (float*)(sm + 52224);
  float* Bl = (float*)(sm + 70656);     // 256
  u16*  WR  = Qc;
  int h = blockIdx.x, c = blockIdx.y;
  int tid = threadIdx.x, wave = tid >> 6, lane = tid & 63;
  size_t ch = (size_t)(c * 16 + h);
  const u16* kb = kn + ((size_t)h << 18) + ((size_t)c << 13);
  const u16* qb = qn + ((size_t)h << 18) + ((size_t)c << 13);
  const u16* vb = vn + ((size_t)h << 18) + ((size_t)c << 13);
#pragma unroll
  for (int s = 0; s < 4; ++s) {
    int e = (tid + (s << 8)) << 3;
    int t = e >> 7, d = e & 127;
    *(u16x8*)&Kc[t * 136 + d] = *(const u16x8*)(kb + e);
    *(u16x8*)&Qc[t * 136 + d] = *(const u16x8*)(qb + e);
    *(u16x8*)&Vc[t * 136 + d] = *(const u16x8*)(vb + e);
  }
  if (tid < 64) Bl[tid] = beta[((c << 6) + tid) * 16 + h];
  __syncthreads();
  int fr = lane & 15, fq = (lane >> 4) << 3, q4 = (lane >> 4) << 2;
  int arow = (wave << 4) + fr;
  f32x4 kk[4], qk[4];
#pragma unroll
  for (int ct = 0; ct < 4; ++ct) { kk[ct] = (f32x4){0.f,0.f,0.f,0.f}; qk[ct] = (f32x4){0.f,0.f,0.f,0.f}; }
#pragma unroll
  for (int ks = 0; ks < 4; ++ks) {
    short8 aK = *(const short8*)&Kc[arow * 136 + (ks << 5) + fq];
    short8 aQ = *(const short8*)&Qc[arow * 136 + (ks << 5) + fq];
#pragma unroll
    for (int ct = 0; ct < 4; ++ct) {
      short8 bK = *(const short8*)&Kc[((ct << 4) + fr) * 136 + (ks << 5) + fq];
      kk[ct] = mfma_bf16(aK, bK, kk[ct]);
      qk[ct] = mfma_bf16(aQ, bK, qk[ct]);
    }
  }
#pragma unroll
  for (int ct = 0; ct < 4; ++ct)
#pragma unroll
    for (int r = 0; r < 4; ++r) {
      int i = (wave << 4) + q4 + r, j = (ct << 4) + fr;
      Gg[(ch << 12) + i * 64 + j] = f2b((j <= i) ? qk[ct][r] : 0.f);
    }
  // K^T into KTl
  {
    int d = tid & 127, tg = tid >> 7;
#pragma unroll
    for (int it = 0; it < 4; ++it) {
      int t0 = (tg + (it << 1)) << 3;
      u16x8 pk;
#pragma unroll
      for (int j = 0; j < 8; ++j) pk[j] = Kc[(t0 + j) * 136 + d];
      *(u16x8*)&KTl[d * 72 + t0] = pk;
    }
  }
  __syncthreads();
#pragma unroll
  for (int it = 0; it < 4; ++it) {
    int idx = tid + (it << 8);
    int row = idx >> 3, j8 = (idx & 7) << 3;
    *(u16x8*)(KTg + (ch << 13) + (row << 6) + j8) = *(const u16x8*)&KTl[row * 72 + j8];
  }
  __syncthreads();
  {
    float bi[4];
#pragma unroll
    for (int r = 0; r < 4; ++r) bi[r] = Bl[(wave << 4) + q4 + r];
#pragma unroll
    for (int ct = 0; ct < 4; ++ct)
#pragma unroll
      for (int r = 0; r < 4; ++r) {
        int i = (wave << 4) + q4 + r, j = (ct << 4) + fr;
        AL[i * 64 + j] = (j < i) ? bi[r] * kk[ct][r] : 0.f;
      }
  }
  __syncthreads();
  float X[64];
  {
    const u16* colp = (tid < 128) ? (Kc + tid) : (Vc + (tid - 128));
#pragma unroll
    for (int t = 0; t < 64; ++t) X[t] = Bl[t] * b2f(colp[t * 136]);
#pragma unroll
    for (int r = 1; r < 64; ++r) {
      float s = 0.f;
      const float* Ar = &AL[r * 64];
      int r4 = r & ~3;
#pragma unroll
      for (int l = 0; l < 64; l += 4)
        if (l + 4 <= r) {
          float4 a = *(const float4*)(Ar + l);
          s += a.x * X[l] + a.y * X[l + 1] + a.z * X[l + 2] + a.w * X[l + 3];
        }
#pragma unroll
      for (int l = 0; l < 4; ++l)
        if (r4 + l < r) s += Ar[r4 + l] * X[r4 + l];
      X[r] -= s;
    }
  }
  __syncthreads();   // Qc dead -> WR overlay
  if (tid < 128) {
#pragma unroll
    for (int t = 0; t < 64; ++t) WR[t * 136 + tid] = f2b(X[t]);
  } else {
    int v = tid - 128;
    u16* dstr = UTg + (ch << 13) + (v << 6);
#pragma unroll
    for (int j = 0; j < 8; ++j) {
      u16x8 p;
#pragma unroll
      for (int e = 0; e < 8; ++e) p[e] = f2b(X[(j << 3) + e]);
      *(u16x8*)(dstr + (j << 3)) = p;
    }
  }
  __syncthreads();
#pragma unroll
  for (int it = 0; it < 4; ++it) {
    int idx = tid + (it << 8);
    int row = idx >> 4, j8 = (idx & 15) << 3;
    *(u16x8*)(Wg + (ch << 13) + (row << 7) + j8) = *(const u16x8*)&WR[row * 136 + j8];
  }
}

// ---------------- sequential chunked delta-rule scan (lean) ----------------
struct Frags { short8 q[4], w[4], g[2], k[4]; u16x4 u; };

DEVI void load_frags(Frags& f, const u16* qh, const u16* Wg, const u16* Gg,
                     const u16* KTg, const u16* UTg, int c, int h,
                     int trow, int fr, int fq, int q4, int w, int vbase) {
  const u16* qb = qh + ((size_t)((c << 6) + trow + fr) << 7) + fq;
#pragma unroll
  for (int ks = 0; ks < 4; ++ks) f.q[ks] = *(const short8*)(qb + (ks << 5));
  size_t ch = (size_t)(c * 16 + h);
  const u16* wb = Wg + (ch << 13) + ((size_t)(trow + fr) << 7) + fq;
#pragma unroll
  for (int ks = 0; ks < 4; ++ks) f.w[ks] = *(const short8*)(wb + (ks << 5));
  const u16* gb = Gg + (ch << 12) + ((size_t)(trow + fr) << 6) + fq;
#pragma unroll
  for (int ks = 0; ks < 2; ++ks) f.g[ks] = *(const short8*)(gb + (ks << 5));
  const u16* kbp = KTg + (ch << 13) + ((size_t)(w << 5) << 6) + fq;
#pragma unroll
  for (int dt = 0; dt < 2; ++dt)
#pragma unroll
    for (int ks = 0; ks < 2; ++ks)
      f.k[(dt << 1) | ks] = *(const short8*)(kbp + ((size_t)((dt << 4) + fr) << 6) + (ks << 5));
  f.u = *(const u16x4*)(UTg + (ch << 13) + ((size_t)(vbase + fr) << 6) + trow + q4);
}

DEVI void chunk_body(int c, Frags& f, u16* ST, u16* DT, u16* oh,
                     int trow, int fr, int fq, int q4, int w, int vbase,
                     f32x4& S0, f32x4& S1) {
#pragma unroll
  for (int r = 0; r < 4; ++r) {
    ST[(q4 + r) * 136 + (w << 5) + fr] = f2b(S0[r]);
    ST[(q4 + r) * 136 + (w << 5) + 16 + fr] = f2b(S1[r]);
  }
  barrier_lds();
  short8 sf[4];
#pragma unroll
  for (int ks = 0; ks < 4; ++ks) sf[ks] = *(const short8*)&ST[fr * 136 + (ks << 5) + fq];
  f32x4 racc = {0.f,0.f,0.f,0.f}, oacc = {0.f,0.f,0.f,0.f};
#pragma unroll
  for (int ks = 0; ks < 4; ++ks) {
    racc = mfma_bf16(f.w[ks], sf[ks], racc);
    oacc = mfma_bf16(f.q[ks], sf[ks], oacc);
  }
#pragma unroll
  for (int r = 0; r < 4; ++r)
    DT[fr * 72 + trow + q4 + r] = f2b(b2f(f.u[r]) - racc[r]);
  barrier_lds();
  short8 df[2];
#pragma unroll
  for (int ks = 0; ks < 2; ++ks) df[ks] = *(const short8*)&DT[fr * 72 + (ks << 5) + fq];
#pragma unroll
  for (int ks = 0; ks < 2; ++ks) {
    oacc = mfma_bf16(f.g[ks], df[ks], oacc);
    S0 = mfma_bf16(df[ks], f.k[ks], S0);
    S1 = mfma_bf16(df[ks], f.k[2 | ks], S1);
  }
#pragma unroll
  for (int r = 0; r < 4; ++r)
    oh[(size_t)((c << 6) + trow + q4 + r) * 128 + vbase + fr] = f2b(oacc[r]);
}

__global__ __launch_bounds__(256, 1)
void k_delta(const u16* __restrict__ qn, const u16* __restrict__ Wg,
             const u16* __restrict__ Gg, const u16* __restrict__ KTg,
             const u16* __restrict__ UTg, u16* __restrict__ o) {
  __shared__ __align__(16) u16 ST[16 * 136];
  __shared__ __align__(16) u16 DT[16 * 72];
  int bx = blockIdx.x;
  int h = bx & 15, vbase = (bx >> 4) << 4;
  int tid = threadIdx.x, w = tid >> 6, lane = tid & 63;
  int fr = lane & 15, fq = (lane >> 4) << 3, q4 = (lane >> 4) << 2;
  int trow = w << 4;
  const u16* qh = qn + ((size_t)h << 18);
  u16* oh = o + ((size_t)h << 18);
  f32x4 S0 = {0.f,0.f,0.f,0.f}, S1 = {0.f,0.f,0.f,0.f};
  Frags fa, fb;
  load_frags(fa, qh, Wg, Gg, KTg, UTg, 0, h, trow, fr, fq, q4, w, vbase);
  for (int c = 0; c < 32; c += 2) {
    int c1 = c + 1, c2 = (c + 2 < 32) ? c + 2 : 31;
    load_frags(fb, qh, Wg, Gg, KTg, UTg, c1, h, trow, fr, fq, q4, w, vbase);
    chunk_body(c, fa, ST, DT, oh, trow, fr, fq, q4, w, vbase, S0, S1);
    load_frags(fa, qh, Wg, Gg, KTg, UTg, c2, h, trow, fr, fq, q4, w, vbase);
    chunk_body(c1, fb, ST, DT, oh, trow, fr, fq, q4, w, vbase, S0, S1);
  }
}

// ---------------- per-head RMSNorm on o (bf16 in), emit bf16 [T][H*128] ----------------
__global__ void k_onorm(const u16* __restrict__ o, const float* __restrict__ onw,
                        u16* __restrict__ onb) {
  int t = blockIdx.x, h = blockIdx.y, d = threadIdx.x;
  float x = b2f(o[((size_t)h << 18) + ((size_t)t << 7) + d]);
  float ss = x * x;
#pragma unroll
  for (int off = 32; off; off >>= 1) ss += __shfl_down(ss, off, 64);
  __shared__ float red[2];
  int lane = d & 63, wv = d >> 6;
  if (lane == 0) red[wv] = ss;
  __syncthreads();
  float tot = red[0] + red[1];
  float y = x * rsqrtf(tot * (1.f / 128.f) + 1e-6f) * onw[d];
  onb[((size_t)t << 11) + (h << 7) + d] = f2b(y);
}

extern "C" void kernel_launch(void* const* d_in, const int* in_sizes, int n_in,
                              void* d_out, int out_size, void* d_ws, size_t ws_size,
                              hipStream_t stream) {
  (void)in_sizes; (void)n_in; (void)out_size; (void)ws_size;
  const float* hs  = (const float*)d_in[0];
  const float* Wq  = (const float*)d_in[1];
  const float* Wk  = (const float*)d_in[2];
  const float* Wv  = (const float*)d_in[3];
  const float* Wb  = (const float*)d_in[4];
  const float* cwq = (const float*)d_in[5];
  const float* cwk = (const float*)d_in[6];
  const float* cwv = (const float*)d_in[7];
  const float* onw = (const float*)d_in[8];
  const float* Wo  = (const float*)d_in[9];
  float* out = (float*)d_out;
  char* ws = (char*)d_ws;
  const size_t MB = 1ull << 20;
  u16*  Xb   = (u16*)(ws);              //  8 MB  hs bf16 [2048][2048]
  u16*  WT   = (u16*)(ws + 8  * MB);    // 24 MB  [Wq|Wk|Wv]^T bf16 [6144][2048]
  u16*  WoT  = (u16*)(ws + 32 * MB);    //  8 MB  Wo^T bf16
  u16*  QKV  = (u16*)(ws + 40 * MB);    // 24 MB  qkv pre-activations (dead after k_conv)
  u16*  Wg   = (u16*)(ws + 40 * MB);    //  8 MB  overlays dead QKV
  u16*  KTg  = (u16*)(ws + 48 * MB);    //  8 MB
  u16*  UTg  = (u16*)(ws + 56 * MB);    //  8 MB
  u16*  qn_  = (u16*)(ws + 64 * MB);    //  8 MB  [16][2048][128]
  u16*  kn_  = (u16*)(ws + 72 * MB);    //  8 MB
  u16*  vn_  = (u16*)(ws + 80 * MB);    //  8 MB
  float* beta= (float*)(ws + 88 * MB);  //  128KB [2048][16]
  u16*  WbT  = (u16*)(ws + 88 * MB + 512 * 1024);  // 64KB [16][2048]
  u16*  Gm   = (u16*)(ws + 89 * MB);    //  4 MB  [32*16][64][64]
  u16*  o_   = (u16*)(ws + 93 * MB);    //  8 MB  bf16 [16][2048][128]
  u16*  onb  = (u16*)(ws + 109 * MB);   //  8 MB  [2048][2048]

  k_cvt<<<4224, 256, 0, stream>>>(hs, Xb, 2048 * 2048 / 4, Wb, WbT);
  k_transpose4<<<dim3(32, 32, 4), 256, 0, stream>>>(
      Wq, Wk, Wv, Wo, WT, WT + 2048 * 2048, WT + 2 * 2048 * 2048, WoT);
  k_gemm_bt<<<dim3(48, 16), 256, 0, stream>>>(Xb, WT, nullptr, QKV, 2048, 6144, 2048, 1);
  k_beta<<<128, 256, 0, stream>>>(Xb, WbT, beta);
  k_conv<<<dim3(2048, 48), 128, 0, stream>>>(QKV, cwq, cwk, cwv, qn_, kn_, vn_);
  k_prep<<<dim3(16, 32), 256, 0, stream>>>(qn_, kn_, vn_, beta, Gm, Wg, KTg, UTg);
  k_delta<<<128, 256, 0, stream>>>(qn_, Wg, Gm, KTg, UTg, o_);
  k_onorm<<<dim3(2048, 16), 128, 0, stream>>>(o_, onw, onb);
  k_gemm_bt64<<<dim3(16, 32), 256, 0, stream>>>(onb, WoT, out, 2048, 2048, 2048);
}

// Round 7
// 346.986 us; speedup vs baseline: 1.7613x; 1.0794x over previous
//
#include <hip/hip_runtime.h>

typedef unsigned short u16;
typedef __attribute__((ext_vector_type(4))) unsigned short u16x4;
typedef __attribute__((ext_vector_type(8))) unsigned short u16x8;
typedef __attribute__((ext_vector_type(8))) short short8;
typedef __attribute__((ext_vector_type(4))) float f32x4;

#define DEVI __device__ __forceinline__

DEVI u16 f2b(float f) {
  union { float f; unsigned u; } x; x.f = f;
  unsigned r = (x.u + 0x7fffu + ((x.u >> 16) & 1u)) >> 16;
  return (u16)r;
}
DEVI float b2f(u16 h) {
  union { unsigned u; float f; } x; x.u = ((unsigned)h) << 16;
  return x.f;
}
DEVI f32x4 mfma_bf16(short8 a, short8 b, f32x4 c) {
  return __builtin_amdgcn_mfma_f32_16x16x32_bf16(a, b, c, 0, 0, 0);
}
DEVI void gl2lds16(const u16* g, u16* l) {
  __builtin_amdgcn_global_load_lds((__attribute__((address_space(1))) void*)g,
                                   (__attribute__((address_space(3))) void*)l,
                                   16, 0, 0);
}
// barrier that drains only LDS (lgkmcnt), NOT vmcnt -> global prefetch stays in flight
DEVI void barrier_lds() {
  asm volatile("s_waitcnt lgkmcnt(0)\n\ts_barrier" ::: "memory");
}

// ---------------- fp32 -> bf16 convert (hidden_states) + WbT build ----------------
__global__ void k_cvt(const float* __restrict__ src, u16* __restrict__ dst, int n4,
                      const float* __restrict__ Wb, u16* __restrict__ WbT) {
  int b = blockIdx.x;
  if (b < 4096) {
    int i = b * 256 + threadIdx.x;
    if (i < n4) {
      float4 v = ((const float4*)src)[i];
      u16x4 r; r.x = f2b(v.x); r.y = f2b(v.y); r.z = f2b(v.z); r.w = f2b(v.w);
      ((u16x4*)dst)[i] = r;
    }
  } else {
    int j = (b - 4096) * 256 + threadIdx.x;   // 0..32767
    int n = j >> 11, k = j & 2047;
    WbT[j] = f2b(Wb[k * 16 + n]);
  }
}

// ---------------- 4x tiled transpose fp32[2048][2048] -> bf16 transposed ----------------
__global__ __launch_bounds__(256)
void k_transpose4(const float* __restrict__ s0, const float* __restrict__ s1,
                  const float* __restrict__ s2, const float* __restrict__ s3,
                  u16* __restrict__ d0, u16* __restrict__ d1,
                  u16* __restrict__ d2, u16* __restrict__ d3) {
  const int RC = 2048;
  const float* src = (blockIdx.z == 0) ? s0 : (blockIdx.z == 1) ? s1 : (blockIdx.z == 2) ? s2 : s3;
  u16* dst = (blockIdx.z == 0) ? d0 : (blockIdx.z == 1) ? d1 : (blockIdx.z == 2) ? d2 : d3;
  __shared__ u16 tile[64 * 66];
  int bx = blockIdx.x << 6, by = blockIdx.y << 6;
  int x = threadIdx.x & 63, g = threadIdx.x >> 6;
#pragma unroll
  for (int i = 0; i < 16; ++i) {
    int r = (i << 2) + g;
    tile[x * 66 + r] = f2b(src[(size_t)(by + r) * RC + bx + x]);  // transposed into LDS
  }
  __syncthreads();
#pragma unroll
  for (int i = 0; i < 16; ++i) {
    int r = (i << 2) + g;
    dst[(size_t)(bx + r) * RC + by + x] = tile[r * 66 + x];       // 128B coalesced rows
  }
}

// ---------------- bf16 MFMA GEMM 128x128: C[M][N] = A[M][K] @ BT[N][K]^T ----------------
__global__ __launch_bounds__(256, 4)
void k_gemm_bt(const u16* __restrict__ A, const u16* __restrict__ BT,
               float* __restrict__ Cf, u16* __restrict__ Cb,
               int M, int N, int K, int outbf) {
  __shared__ __align__(16) u16 As[4096];
  __shared__ __align__(16) u16 Bs[4096];
  const int tid = threadIdx.x, wave = tid >> 6, lane = tid & 63;
  const long bm = (long)blockIdx.y << 7, bn = (long)blockIdx.x << 7;
  const int r0 = (wave << 4) + (lane >> 2);
  const int kof = (((lane & 3) ^ ((lane >> 3) & 3)) << 3);   // swizzled chunk fetch
  const u16* gA = A + (bm + r0) * (long)K + kof;
  const u16* gB = BT + (bn + r0) * (long)K + kof;
  u16* lA = As + (wave << 9);
  u16* lB = Bs + (wave << 9);
  const long stepR = (long)64 * K;
  const int wr = (wave >> 1) << 6, wc = (wave & 1) << 6;
  const int fr = lane & 15, fq = (lane >> 4) << 3;
  const int fqs = fq ^ (((fr >> 1) & 3) << 3);               // read-side inverse swizzle
  f32x4 acc[4][4];
#pragma unroll
  for (int i = 0; i < 4; ++i)
#pragma unroll
    for (int j = 0; j < 4; ++j) acc[i][j] = (f32x4){0.f, 0.f, 0.f, 0.f};
  for (int k0 = 0; k0 < K; k0 += 32) {
    gl2lds16(gA + k0, lA);
    gl2lds16(gA + stepR + k0, lA + 2048);
    gl2lds16(gB + k0, lB);
    gl2lds16(gB + stepR + k0, lB + 2048);
    __syncthreads();
    short8 af[4], bfr[4];
#pragma unroll
    for (int t = 0; t < 4; ++t)
      af[t] = *(const short8*)&As[(wr + (t << 4) + fr) * 32 + fqs];
#pragma unroll
    for (int t = 0; t < 4; ++t)
      bfr[t] = *(const short8*)&Bs[(wc + (t << 4) + fr) * 32 + fqs];
#pragma unroll
    for (int i = 0; i < 4; ++i)
#pragma unroll
      for (int j = 0; j < 4; ++j)
        acc[i][j] = mfma_bf16(af[i], bfr[j], acc[i][j]);
    __syncthreads();
  }
  const int er = (lane >> 4) << 2, ec = lane & 15;
#pragma unroll
  for (int i = 0; i < 4; ++i)
#pragma unroll
    for (int j = 0; j < 4; ++j)
#pragma unroll
      for (int r = 0; r < 4; ++r) {
        long row = bm + wr + (i << 4) + er + r;
        long col = bn + wc + (j << 4) + ec;
        if (outbf) Cb[row * N + col] = f2b(acc[i][j][r]);
        else       Cf[row * N + col] = acc[i][j][r];
      }
}

// ---------------- bf16 MFMA GEMM 64x64 tile (max block count for small GEMMs) ----------------
__global__ __launch_bounds__(256, 4)
void k_gemm_wo(const u16* __restrict__ A, const u16* __restrict__ BT,
               float* __restrict__ Cf, int M, int N, int K) {
  __shared__ __align__(16) u16 As[2048];
  __shared__ __align__(16) u16 Bs[2048];
  const int tid = threadIdx.x, wave = tid >> 6, lane = tid & 63;
  const long bm = (long)blockIdx.y << 6, bn = (long)blockIdx.x << 6;
  const int r0 = (wave << 4) + (lane >> 2);
  const int kof = (((lane & 3) ^ ((lane >> 3) & 3)) << 3);
  const u16* gA = A + (bm + r0) * (long)K + kof;
  const u16* gB = BT + (bn + r0) * (long)K + kof;
  u16* lA = As + (wave << 9);
  u16* lB = Bs + (wave << 9);
  const int wr = (wave >> 1) << 5, wc = (wave & 1) << 5;
  const int fr = lane & 15, fq = (lane >> 4) << 3;
  const int fqs = fq ^ (((fr >> 1) & 3) << 3);
  f32x4 acc[2][2];
#pragma unroll
  for (int i = 0; i < 2; ++i)
#pragma unroll
    for (int j = 0; j < 2; ++j) acc[i][j] = (f32x4){0.f, 0.f, 0.f, 0.f};
  for (int k0 = 0; k0 < K; k0 += 32) {
    gl2lds16(gA + k0, lA);
    gl2lds16(gB + k0, lB);
    __syncthreads();
    short8 af[2], bfr[2];
#pragma unroll
    for (int t = 0; t < 2; ++t) {
      af[t]  = *(const short8*)&As[(wr + (t << 4) + fr) * 32 + fqs];
      bfr[t] = *(const short8*)&Bs[(wc + (t << 4) + fr) * 32 + fqs];
    }
#pragma unroll
    for (int i = 0; i < 2; ++i)
#pragma unroll
      for (int j = 0; j < 2; ++j)
        acc[i][j] = mfma_bf16(af[i], bfr[j], acc[i][j]);
    __syncthreads();
  }
  const int er = (lane >> 4) << 2, ec = lane & 15;
#pragma unroll
  for (int i = 0; i < 2; ++i)
#pragma unroll
    for (int j = 0; j < 2; ++j)
#pragma unroll
      for (int r = 0; r < 4; ++r) {
        long row = bm + wr + (i << 4) + er + r;
        long col = bn + wc + (j << 4) + ec;
        Cf[row * N + col] = acc[i][j][r];
      }
}

// ---------------- beta = sigmoid(hs @ Wb) via MFMA ----------------
__global__ __launch_bounds__(256, 4)
void k_beta(const u16* __restrict__ Xb, const u16* __restrict__ WbT,
            float* __restrict__ beta) {
  __shared__ float part[4][256];
  int tid = threadIdx.x, w = tid >> 6, lane = tid & 63;
  int t0 = blockIdx.x << 4;
  int fr = lane & 15, fq = (lane >> 4) << 3;
  const u16* ap = Xb + (size_t)(t0 + fr) * 2048 + (w << 9) + fq;
  const u16* bp = WbT + (size_t)fr * 2048 + (w << 9) + fq;
  f32x4 acc = {0.f, 0.f, 0.f, 0.f};
#pragma unroll
  for (int ks = 0; ks < 16; ++ks)
    acc = mfma_bf16(*(const short8*)(ap + (ks << 5)), *(const short8*)(bp + (ks << 5)), acc);
  int er = (lane >> 4) << 2;
#pragma unroll
  for (int r = 0; r < 4; ++r) part[w][(er + r) * 16 + fr] = acc[r];
  __syncthreads();
  float s = part[0][tid] + part[1][tid] + part[2][tid] + part[3][tid];
  beta[(t0 << 4) + tid] = 1.f / (1.f + __expf(-s));
}

// ---------------- causal conv(K=4) + SiLU + l2norm, tile version ----------------
// grid (32, 48): 64-token tile x (kind,head). thread = (token t, 32-d group dg).
__global__ __launch_bounds__(256, 4)
void k_conv(const u16* __restrict__ qkv,
            const float* __restrict__ cwq, const float* __restrict__ cwk,
            const float* __restrict__ cwv,
            u16* __restrict__ qn, u16* __restrict__ kn, u16* __restrict__ vn) {
  __shared__ __align__(16) u16 xs[67 * 136];
  __shared__ float wf[128 * 4];
  int tt = blockIdx.x, s = blockIdx.y;
  int kind = s >> 4, h = s & 15;
  int t0 = tt << 6;
  int col = (kind << 11) + (h << 7);
  int tid = threadIdx.x;
  const float* cw = (kind == 0) ? cwq : ((kind == 1) ? cwk : cwv);
  if (tid < 128) *(float4*)&wf[tid << 2] = *(const float4*)(cw + (size_t)((h << 7) + tid) * 4);
  // stage rows t0-3 .. t0+63 (67 rows x 128 d), coalesced 16B chunks
  for (int i = tid; i < 1072; i += 256) {
    int prow = i >> 4, c8 = (i & 15) << 3;
    int g = t0 - 3 + prow;
    u16x8 v = {0, 0, 0, 0, 0, 0, 0, 0};
    if (g >= 0) v = *(const u16x8*)(qkv + (size_t)g * 6144 + col + c8);
    *(u16x8*)&xs[prow * 136 + c8] = v;
  }
  __syncthreads();
  int t = tid >> 2, dg = tid & 3;
  float y[32];
  float ss = 0.f;
#pragma unroll
  for (int e8 = 0; e8 < 4; ++e8) {
    int d0 = (dg << 5) + (e8 << 3);
    u16x8 a0 = *(const u16x8*)&xs[(t + 0) * 136 + d0];
    u16x8 a1 = *(const u16x8*)&xs[(t + 1) * 136 + d0];
    u16x8 a2 = *(const u16x8*)&xs[(t + 2) * 136 + d0];
    u16x8 a3 = *(const u16x8*)&xs[(t + 3) * 136 + d0];
#pragma unroll
    for (int e = 0; e < 8; ++e) {
      float4 w = *(const float4*)&wf[(d0 + e) << 2];
      float v = b2f(a0[e]) * w.x + b2f(a1[e]) * w.y + b2f(a2[e]) * w.z + b2f(a3[e]) * w.w;
      v = v / (1.f + __expf(-v));   // SiLU
      y[(e8 << 3) + e] = v;
      ss += v * v;
    }
  }
  float sc = 1.f;
  if (kind < 2) {
    ss += __shfl_xor(ss, 1);
    ss += __shfl_xor(ss, 2);
    sc = rsqrtf(ss + 1e-6f);
    if (kind == 0) sc *= 0.08838834764831843f;  // 128^-0.5
  }
  u16* dst = (kind == 0) ? qn : ((kind == 1) ? kn : vn);
  u16* dp = dst + ((size_t)h << 18) + ((size_t)(t0 + t) << 7) + (dg << 5);
#pragma unroll
  for (int e8 = 0; e8 < 4; ++e8) {
    u16x8 p;
#pragma unroll
    for (int e = 0; e < 8; ++e) p[e] = f2b(y[(e8 << 3) + e] * sc);
    *(u16x8*)(dp + (e8 << 3)) = p;
  }
}

// ---------------- per-(chunk,head) parallel prep (v3) ----------------
__global__ __launch_bounds__(256, 2)
void k_prep(const u16* __restrict__ qn, const u16* __restrict__ kn, const u16* __restrict__ vn,
            const float* __restrict__ beta,
            u16* __restrict__ Gg, u16* __restrict__ Wg,
            u16* __restrict__ KTg, u16* __restrict__ UTg) {
  __shared__ __align__(16) char sm[70912];
  u16*  Kc  = (u16*)sm;                 // 64*136*2 = 17408
  u16*  Qc  = (u16*)(sm + 17408);       // 17408 ; overlay: WR
  u16*  Vc  = (u16*)(sm + 34816);       // 17408
  u16*  KTl = (u16*)(sm + 52224);       // 128*72*2 = 18432 ; overlay: AL (64*64*4)
  float* AL = (float*)(sm + 52224);
  float* Bl = (float*)(sm + 70656);     // 256
  u16*  WR  = Qc;
  int h = blockIdx.x, c = blockIdx.y;
  int tid = threadIdx.x, wave = tid >> 6, lane = tid & 63;
  size_t ch = (size_t)(c * 16 + h);
  const u16* kb = kn + ((size_t)h << 18) + ((size_t)c << 13);
  const u16* qb = qn + ((size_t)h << 18) + ((size_t)c << 13);
  const u16* vb = vn + ((size_t)h << 18) + ((size_t)c << 13);
#pragma unroll
  for (int s = 0; s < 4; ++s) {
    int e = (tid + (s << 8)) << 3;
    int t = e >> 7, d = e & 127;
    *(u16x8*)&Kc[t * 136 + d] = *(const u16x8*)(kb + e);
    *(u16x8*)&Qc[t * 136 + d] = *(const u16x8*)(qb + e);
    *(u16x8*)&Vc[t * 136 + d] = *(const u16x8*)(vb + e);
  }
  if (tid < 64) Bl[tid] = beta[((c << 6) + tid) * 16 + h];
  __syncthreads();
  int fr = lane & 15, fq = (lane >> 4) << 3, q4 = (lane >> 4) << 2;
  int arow = (wave << 4) + fr;
  f32x4 kk[4], qk[4];
#pragma unroll
  for (int ct = 0; ct < 4; ++ct) { kk[ct] = (f32x4){0.f,0.f,0.f,0.f}; qk[ct] = (f32x4){0.f,0.f,0.f,0.f}; }
#pragma unroll
  for (int ks = 0; ks < 4; ++ks) {
    short8 aK = *(const short8*)&Kc[arow * 136 + (ks << 5) + fq];
    short8 aQ = *(const short8*)&Qc[arow * 136 + (ks << 5) + fq];
#pragma unroll
    for (int ct = 0; ct < 4; ++ct) {
      short8 bK = *(const short8*)&Kc[((ct << 4) + fr) * 136 + (ks << 5) + fq];
      kk[ct] = mfma_bf16(aK, bK, kk[ct]);
      qk[ct] = mfma_bf16(aQ, bK, qk[ct]);
    }
  }
#pragma unroll
  for (int ct = 0; ct < 4; ++ct)
#pragma unroll
    for (int r = 0; r < 4; ++r) {
      int i = (wave << 4) + q4 + r, j = (ct << 4) + fr;
      Gg[(ch << 12) + i * 64 + j] = f2b((j <= i) ? qk[ct][r] : 0.f);
    }
  // K^T into KTl
  {
    int d = tid & 127, tg = tid >> 7;
#pragma unroll
    for (int it = 0; it < 4; ++it) {
      int t0 = (tg + (it << 1)) << 3;
      u16x8 pk;
#pragma unroll
      for (int j = 0; j < 8; ++j) pk[j] = Kc[(t0 + j) * 136 + d];
      *(u16x8*)&KTl[d * 72 + t0] = pk;
    }
  }
  __syncthreads();
#pragma unroll
  for (int it = 0; it < 4; ++it) {
    int idx = tid + (it << 8);
    int row = idx >> 3, j8 = (idx & 7) << 3;
    *(u16x8*)(KTg + (ch << 13) + (row << 6) + j8) = *(const u16x8*)&KTl[row * 72 + j8];
  }
  __syncthreads();
  {
    float bi[4];
#pragma unroll
    for (int r = 0; r < 4; ++r) bi[r] = Bl[(wave << 4) + q4 + r];
#pragma unroll
    for (int ct = 0; ct < 4; ++ct)
#pragma unroll
      for (int r = 0; r < 4; ++r) {
        int i = (wave << 4) + q4 + r, j = (ct << 4) + fr;
        AL[i * 64 + j] = (j < i) ? bi[r] * kk[ct][r] : 0.f;
      }
  }
  __syncthreads();
  float X[64];
  {
    const u16* colp = (tid < 128) ? (Kc + tid) : (Vc + (tid - 128));
#pragma unroll
    for (int t = 0; t < 64; ++t) X[t] = Bl[t] * b2f(colp[t * 136]);
#pragma unroll
    for (int r = 1; r < 64; ++r) {
      float s = 0.f;
      const float* Ar = &AL[r * 64];
      int r4 = r & ~3;
#pragma unroll
      for (int l = 0; l < 64; l += 4)
        if (l + 4 <= r) {
          float4 a = *(const float4*)(Ar + l);
          s += a.x * X[l] + a.y * X[l + 1] + a.z * X[l + 2] + a.w * X[l + 3];
        }
#pragma unroll
      for (int l = 0; l < 4; ++l)
        if (r4 + l < r) s += Ar[r4 + l] * X[r4 + l];
      X[r] -= s;
    }
  }
  __syncthreads();   // Qc dead -> WR overlay
  if (tid < 128) {
#pragma unroll
    for (int t = 0; t < 64; ++t) WR[t * 136 + tid] = f2b(X[t]);
  } else {
    int v = tid - 128;
    u16* dstr = UTg + (ch << 13) + (v << 6);
#pragma unroll
    for (int j = 0; j < 8; ++j) {
      u16x8 p;
#pragma unroll
      for (int e = 0; e < 8; ++e) p[e] = f2b(X[(j << 3) + e]);
      *(u16x8*)(dstr + (j << 3)) = p;
    }
  }
  __syncthreads();
#pragma unroll
  for (int it = 0; it < 4; ++it) {
    int idx = tid + (it << 8);
    int row = idx >> 4, j8 = (idx & 15) << 3;
    *(u16x8*)(Wg + (ch << 13) + (row << 7) + j8) = *(const u16x8*)&WR[row * 136 + j8];
  }
}

// ---------------- sequential chunked delta-rule scan (lean) ----------------
struct Frags { short8 q[4], w[4], g[2], k[4]; u16x4 u; };

DEVI void load_frags(Frags& f, const u16* qh, const u16* Wg, const u16* Gg,
                     const u16* KTg, const u16* UTg, int c, int h,
                     int trow, int fr, int fq, int q4, int w, int vbase) {
  const u16* qb = qh + ((size_t)((c << 6) + trow + fr) << 7) + fq;
#pragma unroll
  for (int ks = 0; ks < 4; ++ks) f.q[ks] = *(const short8*)(qb + (ks << 5));
  size_t ch = (size_t)(c * 16 + h);
  const u16* wb = Wg + (ch << 13) + ((size_t)(trow + fr) << 7) + fq;
#pragma unroll
  for (int ks = 0; ks < 4; ++ks) f.w[ks] = *(const short8*)(wb + (ks << 5));
  const u16* gb = Gg + (ch << 12) + ((size_t)(trow + fr) << 6) + fq;
#pragma unroll
  for (int ks = 0; ks < 2; ++ks) f.g[ks] = *(const short8*)(gb + (ks << 5));
  const u16* kbp = KTg + (ch << 13) + ((size_t)(w << 5) << 6) + fq;
#pragma unroll
  for (int dt = 0; dt < 2; ++dt)
#pragma unroll
    for (int ks = 0; ks < 2; ++ks)
      f.k[(dt << 1) | ks] = *(const short8*)(kbp + ((size_t)((dt << 4) + fr) << 6) + (ks << 5));
  f.u = *(const u16x4*)(UTg + (ch << 13) + ((size_t)(vbase + fr) << 6) + trow + q4);
}

DEVI void chunk_body(int c, Frags& f, u16* ST, u16* DT, u16* oh,
                     int trow, int fr, int fq, int q4, int w, int vbase,
                     f32x4& S0, f32x4& S1) {
#pragma unroll
  for (int r = 0; r < 4; ++r) {
    ST[(q4 + r) * 136 + (w << 5) + fr] = f2b(S0[r]);
    ST[(q4 + r) * 136 + (w << 5) + 16 + fr] = f2b(S1[r]);
  }
  barrier_lds();
  short8 sf[4];
#pragma unroll
  for (int ks = 0; ks < 4; ++ks) sf[ks] = *(const short8*)&ST[fr * 136 + (ks << 5) + fq];
  f32x4 racc = {0.f,0.f,0.f,0.f}, oacc = {0.f,0.f,0.f,0.f};
#pragma unroll
  for (int ks = 0; ks < 4; ++ks) {
    racc = mfma_bf16(f.w[ks], sf[ks], racc);
    oacc = mfma_bf16(f.q[ks], sf[ks], oacc);
  }
#pragma unroll
  for (int r = 0; r < 4; ++r)
    DT[fr * 72 + trow + q4 + r] = f2b(b2f(f.u[r]) - racc[r]);
  barrier_lds();
  short8 df[2];
#pragma unroll
  for (int ks = 0; ks < 2; ++ks) df[ks] = *(const short8*)&DT[fr * 72 + (ks << 5) + fq];
#pragma unroll
  for (int ks = 0; ks < 2; ++ks) {
    oacc = mfma_bf16(f.g[ks], df[ks], oacc);
    S0 = mfma_bf16(df[ks], f.k[ks], S0);
    S1 = mfma_bf16(df[ks], f.k[2 | ks], S1);
  }
#pragma unroll
  for (int r = 0; r < 4; ++r)
    oh[(size_t)((c << 6) + trow + q4 + r) * 128 + vbase + fr] = f2b(oacc[r]);
}

__global__ __launch_bounds__(256, 1)
void k_delta(const u16* __restrict__ qn, const u16* __restrict__ Wg,
             const u16* __restrict__ Gg, const u16* __restrict__ KTg,
             const u16* __restrict__ UTg, u16* __restrict__ o) {
  __shared__ __align__(16) u16 ST[16 * 136];
  __shared__ __align__(16) u16 DT[16 * 72];
  int bx = blockIdx.x;
  int h = bx & 15, vbase = (bx >> 4) << 4;
  int tid = threadIdx.x, w = tid >> 6, lane = tid & 63;
  int fr = lane & 15, fq = (lane >> 4) << 3, q4 = (lane >> 4) << 2;
  int trow = w << 4;
  const u16* qh = qn + ((size_t)h << 18);
  u16* oh = o + ((size_t)h << 18);
  f32x4 S0 = {0.f,0.f,0.f,0.f}, S1 = {0.f,0.f,0.f,0.f};
  Frags fa, fb;
  load_frags(fa, qh, Wg, Gg, KTg, UTg, 0, h, trow, fr, fq, q4, w, vbase);
  for (int c = 0; c < 32; c += 2) {
    int c1 = c + 1, c2 = (c + 2 < 32) ? c + 2 : 31;
    load_frags(fb, qh, Wg, Gg, KTg, UTg, c1, h, trow, fr, fq, q4, w, vbase);
    chunk_body(c, fa, ST, DT, oh, trow, fr, fq, q4, w, vbase, S0, S1);
    load_frags(fa, qh, Wg, Gg, KTg, UTg, c2, h, trow, fr, fq, q4, w, vbase);
    chunk_body(c1, fb, ST, DT, oh, trow, fr, fq, q4, w, vbase, S0, S1);
  }
}

// ---------------- per-head RMSNorm on o (bf16), tile version ----------------
// grid (32, 16): 64-token tile x head. thread = (token, 32-d group).
__global__ __launch_bounds__(256, 4)
void k_onorm(const u16* __restrict__ o, const float* __restrict__ onw,
             u16* __restrict__ onb) {
  __shared__ float wl[128];
  int tt = blockIdx.x, h = blockIdx.y, tid = threadIdx.x;
  if (tid < 128) wl[tid] = onw[tid];
  __syncthreads();
  int t = tid >> 2, dg = tid & 3;
  const u16* src = o + ((size_t)h << 18) + ((size_t)((tt << 6) + t) << 7) + (dg << 5);
  u16x8 a[4];
  float ss = 0.f;
#pragma unroll
  for (int e8 = 0; e8 < 4; ++e8) {
    a[e8] = *(const u16x8*)(src + (e8 << 3));
#pragma unroll
    for (int e = 0; e < 8; ++e) { float x = b2f(a[e8][e]); ss += x * x; }
  }
  ss += __shfl_xor(ss, 1);
  ss += __shfl_xor(ss, 2);
  float inv = rsqrtf(ss * (1.f / 128.f) + 1e-6f);
  u16* dp = onb + ((size_t)((tt << 6) + t) << 11) + (h << 7) + (dg << 5);
#pragma unroll
  for (int e8 = 0; e8 < 4; ++e8) {
    u16x8 p;
#pragma unroll
    for (int e = 0; e < 8; ++e)
      p[e] = f2b(b2f(a[e8][e]) * inv * wl[(dg << 5) + (e8 << 3) + e]);
    *(u16x8*)(dp + (e8 << 3)) = p;
  }
}

extern "C" void kernel_launch(void* const* d_in, const int* in_sizes, int n_in,
                              void* d_out, int out_size, void* d_ws, size_t ws_size,
                              hipStream_t stream) {
  (void)in_sizes; (void)n_in; (void)out_size; (void)ws_size;
  const float* hs  = (const float*)d_in[0];
  const float* Wq  = (const float*)d_in[1];
  const float* Wk  = (const float*)d_in[2];
  const float* Wv  = (const float*)d_in[3];
  const float* Wb  = (const float*)d_in[4];
  const float* cwq = (const float*)d_in[5];
  const float* cwk = (const float*)d_in[6];
  const float* cwv = (const float*)d_in[7];
  const float* onw = (const float*)d_in[8];
  const float* Wo  = (const float*)d_in[9];
  float* out = (float*)d_out;
  char* ws = (char*)d_ws;
  const size_t MB = 1ull << 20;
  u16*  Xb   = (u16*)(ws);              //  8 MB  hs bf16 [2048][2048]
  u16*  WT   = (u16*)(ws + 8  * MB);    // 24 MB  [Wq|Wk|Wv]^T bf16 [6144][2048]
  u16*  WoT  = (u16*)(ws + 32 * MB);    //  8 MB  Wo^T bf16
  u16*  QKV  = (u16*)(ws + 40 * MB);    // 24 MB  qkv pre-activations (dead after k_conv)
  u16*  Wg   = (u16*)(ws + 40 * MB);    //  8 MB  overlays dead QKV
  u16*  KTg  = (u16*)(ws + 48 * MB);    //  8 MB
  u16*  UTg  = (u16*)(ws + 56 * MB);    //  8 MB
  u16*  qn_  = (u16*)(ws + 64 * MB);    //  8 MB  [16][2048][128]
  u16*  kn_  = (u16*)(ws + 72 * MB);    //  8 MB
  u16*  vn_  = (u16*)(ws + 80 * MB);    //  8 MB
  float* beta= (float*)(ws + 88 * MB);  //  128KB [2048][16]
  u16*  WbT  = (u16*)(ws + 88 * MB + 512 * 1024);  // 64KB [16][2048]
  u16*  Gm   = (u16*)(ws + 89 * MB);    //  4 MB  [32*16][64][64]
  u16*  o_   = (u16*)(ws + 93 * MB);    //  8 MB  bf16 [16][2048][128]
  u16*  onb  = (u16*)(ws + 109 * MB);   //  8 MB  [2048][2048]

  k_cvt<<<4224, 256, 0, stream>>>(hs, Xb, 2048 * 2048 / 4, Wb, WbT);
  k_transpose4<<<dim3(32, 32, 4), 256, 0, stream>>>(
      Wq, Wk, Wv, Wo, WT, WT + 2048 * 2048, WT + 2 * 2048 * 2048, WoT);
  k_gemm_bt<<<dim3(48, 16), 256, 0, stream>>>(Xb, WT, nullptr, QKV, 2048, 6144, 2048, 1);
  k_beta<<<128, 256, 0, stream>>>(Xb, WbT, beta);
  k_conv<<<dim3(32, 48), 256, 0, stream>>>(QKV, cwq, cwk, cwv, qn_, kn_, vn_);
  k_prep<<<dim3(16, 32), 256, 0, stream>>>(qn_, kn_, vn_, beta, Gm, Wg, KTg, UTg);
  k_delta<<<128, 256, 0, stream>>>(qn_, Wg, Gm, KTg, UTg, o_);
  k_onorm<<<dim3(32, 16), 256, 0, stream>>>(o_, onw, onb);
  k_gemm_wo<<<dim3(32, 32), 256, 0, stream>>>(onb, WoT, out, 2048, 2048, 2048);
}